// Round 13
// baseline (155.901 us; speedup 1.0000x reference)
//
#include <hip/hip_runtime.h>

#define NB 8
#define NT 64
#define NS 128
#define TDIM 512
#define NV 32000
#define NEXT 32256
#define NBT 512
#define LNEPS 1e-5f
#define CLG 2.8853900817779268f  // 2*log2(e)

typedef unsigned short u16;
typedef __attribute__((ext_vector_type(8))) short short8;
typedef __attribute__((ext_vector_type(4))) float f32x4;

__device__ __forceinline__ float bf2f(u16 u){ union{unsigned int i; float f;} v; v.i = ((unsigned int)u)<<16; return v.f; }
__device__ __forceinline__ u16 f2bf(float f){ union{float f; unsigned int i;} v; v.f=f; unsigned int r = v.i + 0x7FFFu + ((v.i>>16)&1u); return (u16)(r>>16); }
__device__ __forceinline__ float wsum(float v){
  v += __shfl_xor(v,32); v += __shfl_xor(v,16); v += __shfl_xor(v,8);
  v += __shfl_xor(v,4);  v += __shfl_xor(v,2);  v += __shfl_xor(v,1); return v; }
__device__ __forceinline__ float wmax(float v){
  v = fmaxf(v,__shfl_xor(v,32)); v = fmaxf(v,__shfl_xor(v,16)); v = fmaxf(v,__shfl_xor(v,8));
  v = fmaxf(v,__shfl_xor(v,4));  v = fmaxf(v,__shfl_xor(v,2));  v = fmaxf(v,__shfl_xor(v,1)); return v; }

#define GL2LDS(gp, lp) __builtin_amdgcn_global_load_lds( \
    (__attribute__((address_space(1))) void*)(void*)(gp), \
    (__attribute__((address_space(3))) void*)(void*)(lp), 16, 0, 0)

// ---------------- f32 -> bf16 cast of ALL GEMM operands + fused masks (R9 version) ----------------
__global__ __launch_bounds__(256) void k_cast(const float* tgt, const float* s1, const float* s2,
    const float* a1w, const float* a2w, const float* ofw,
    u16* tgtb, u16* s1b, u16* s2b, u16* a1wb, u16* a2wb, u16* ofwb, float* msk)
{
  int blk = blockIdx.x;
  const float* src; u16* dst; int base;
  if(blk < 128){       src=tgt; dst=tgtb;  base=blk; }
  else if(blk < 384){  src=s1;  dst=s1b;   base=blk-128; }
  else if(blk < 640){  src=s2;  dst=s2b;   base=blk-384; }
  else if(blk < 896){  src=a1w; dst=a1wb;  base=blk-640; }
  else if(blk < 1152){ src=a2w; dst=a2wb;  base=blk-896; }
  else {               src=ofw; dst=ofwb;  base=blk-1152; }
  size_t off = (size_t)base*2048 + (size_t)threadIdx.x*8;
  float4 x0 = *(const float4*)(src+off);
  float4 x1 = *(const float4*)(src+off+4);
  float xs[8] = {x0.x,x0.y,x0.z,x0.w,x1.x,x1.y,x1.z,x1.w};
  short8 r;
  #pragma unroll
  for(int j=0;j<8;++j) r[j] = (short)f2bf(xs[j]);
  *(short8*)(dst+off) = r;
  if(blk < 640){
    float a = 0.f;
    #pragma unroll
    for(int j=0;j<8;++j) a += fabsf(xs[j]);
    a = wsum(a);
    if((threadIdx.x&63)==0){
      int w = threadIdx.x>>6;
      int midx;
      if(blk<128)      midx = blk*4 + w;
      else if(blk<384) midx = 512 + (blk-128)*4 + w;
      else             midx = 1536 + (blk-384)*4 + w;
      msk[midx] = (a>0.f) ? 1.f : 0.f;
    }
  }
}

// ---------------- MFMA GEMM core (k_proj only) ----------------
template<int MODE> // 2: f32 (acc+bias?)*scale
__device__ __forceinline__ void gemm_core(const u16* A, int lda, const u16* W, int ldw,
    float* Cf, int ldc, const float* bias, int K, int bm, int bn, float scale)
{
  __shared__ u16 Al[128*32];
  __shared__ u16 Wl[128*32];
  const int tid = threadIdx.x, lane = tid&63, wv = tid>>6;
  const int wm = wv>>1, wn = wv&1;
  const int fr = lane&15, fq = lane>>4;
  const int lrow = lane>>2;
  const int lcol = (lane&3)*8;
  f32x4 acc[4][4] = {};
  for(int k0=0;k0<K;k0+=32){
    #pragma unroll
    for(int r=0;r<2;++r){
      int c = wv + 4*r;
      int row = c*16 + lrow;
      const u16* ga = A + (size_t)(bm+row)*lda + k0 + lcol;
      const u16* gw = W + (size_t)(bn+row)*ldw + k0 + lcol;
      GL2LDS(ga, &Al[c*512]);
      GL2LDS(gw, &Wl[c*512]);
    }
    __syncthreads();
    short8 af[4], bfr[4];
    #pragma unroll
    for(int m=0;m<4;++m) af[m] = *(const short8*)&Al[(wm*64 + m*16 + fr)*32 + fq*8];
    #pragma unroll
    for(int n=0;n<4;++n) bfr[n] = *(const short8*)&Wl[(wn*64 + n*16 + fr)*32 + fq*8];
    #pragma unroll
    for(int m=0;m<4;++m)
      #pragma unroll
      for(int n=0;n<4;++n)
        acc[m][n] = __builtin_amdgcn_mfma_f32_16x16x32_bf16(af[m], bfr[n], acc[m][n], 0,0,0);
    __syncthreads();
  }
  #pragma unroll
  for(int m=0;m<4;++m)
    #pragma unroll
    for(int n=0;n<4;++n)
      #pragma unroll
      for(int i=0;i<4;++i){
        int row = bm + wm*64 + m*16 + fq*4 + i;
        int col = bn + wn*64 + n*16 + fr;
        float bv = bias ? bias[col] : 0.f;
        Cf[(size_t)row*ldc + col] = (acc[m][n][i] + bv)*scale;
      }
}

__global__ __launch_bounds__(256) void k_proj(const u16* tgt, const u16* s1, const u16* s2,
    const u16* w1, const u16* w2, const float* b1, const float* b2,
    float* sq1, float* sk1, float* sq2, float* sk2)
{
  int z = blockIdx.z;
  int Mt = (z&1) ? 1024 : 512;
  int bm = blockIdx.y*128; if(bm >= Mt) return;
  const u16* A = (z&1) ? ((z>>1) ? s2 : s1) : tgt;
  const u16* W = ((z>>1) ? w2 : w1) + ((z&1) ? TDIM : 0);
  float* Cf = (z==0) ? sq1 : (z==1) ? sk1 : (z==2) ? sq2 : sk2;
  const float* bias = (z&1) ? nullptr : ((z>>1) ? b2 : b1);
  gemm_core<2>(A, TDIM, W, 2*TDIM, Cf, TDIM, bias, TDIM, bm, blockIdx.x*128, CLG);
}

// ---------------- k_big: 128x128 tile, NO LDS staging, NO main-loop barriers ----------------
// Fragments loaded directly from global (bf16 A and W); 2x-unrolled ping-pong for load/MFMA overlap.
// K accumulation order identical to LDS version -> bit-identical output.
__global__ __launch_bounds__(256) void k_big(const u16* A, const u16* W, const float* bias,
                                             u16* logits, float2* pstats)
{
  int lid = (blockIdx.x&7)*125 + (blockIdx.x>>3);
  int bm = (lid&3)*128, bn = (lid>>2)*128;
  __shared__ float ps_s[2][128], pq_s[2][128];
  const int tid = threadIdx.x, lane = tid&63, wv = tid>>6;
  const int wm = wv>>1, wn = wv&1;
  const int fr = lane&15, fq = lane>>4;

  const u16* Ab = A + (size_t)(bm + wm*64 + fr)*512 + fq*8;
  const u16* Wb = W + (size_t)(bn + wn*64 + fr)*512 + fq*8;

  f32x4 acc[4][4] = {};
  short8 afA[4], bfA[4], afB[4], bfB[4];
  #pragma unroll
  for(int m=0;m<4;++m) afA[m] = *(const short8*)(Ab + (size_t)(m*16)*512);
  #pragma unroll
  for(int n=0;n<4;++n) bfA[n] = *(const short8*)(Wb + (size_t)(n*16)*512);

  for(int k0=0; k0<512; k0+=64){
    #pragma unroll
    for(int m=0;m<4;++m) afB[m] = *(const short8*)(Ab + (size_t)(m*16)*512 + k0+32);
    #pragma unroll
    for(int n=0;n<4;++n) bfB[n] = *(const short8*)(Wb + (size_t)(n*16)*512 + k0+32);
    #pragma unroll
    for(int m=0;m<4;++m)
      #pragma unroll
      for(int n=0;n<4;++n)
        acc[m][n] = __builtin_amdgcn_mfma_f32_16x16x32_bf16(afA[m], bfA[n], acc[m][n], 0,0,0);
    if(k0+64 < 512){
      #pragma unroll
      for(int m=0;m<4;++m) afA[m] = *(const short8*)(Ab + (size_t)(m*16)*512 + k0+64);
      #pragma unroll
      for(int n=0;n<4;++n) bfA[n] = *(const short8*)(Wb + (size_t)(n*16)*512 + k0+64);
    }
    #pragma unroll
    for(int m=0;m<4;++m)
      #pragma unroll
      for(int n=0;n<4;++n)
        acc[m][n] = __builtin_amdgcn_mfma_f32_16x16x32_bf16(afB[m], bfB[n], acc[m][n], 0,0,0);
  }

  // epilogue: bf16 C-write + row sum/sumsq partials (same as R9)
  #pragma unroll
  for(int m=0;m<4;++m){
    float rs_[4]={0,0,0,0}, rq_[4]={0,0,0,0};
    #pragma unroll
    for(int n=0;n<4;++n)
      #pragma unroll
      for(int i=0;i<4;++i){
        int row = bm + wm*64 + m*16 + fq*4 + i;
        int col = bn + wn*64 + n*16 + fr;
        float v = acc[m][n][i] + bias[col];
        logits[(size_t)row*NV + col] = f2bf(v);
        rs_[i] += v; rq_[i] += v*v;
      }
    #pragma unroll
    for(int i=0;i<4;++i){
      float a=rs_[i], q=rq_[i];
      a+=__shfl_xor(a,1); a+=__shfl_xor(a,2); a+=__shfl_xor(a,4); a+=__shfl_xor(a,8);
      q+=__shfl_xor(q,1); q+=__shfl_xor(q,2); q+=__shfl_xor(q,4); q+=__shfl_xor(q,8);
      if(fr==0){ int lr = wm*64 + m*16 + fq*4 + i; ps_s[wn][lr]=a; pq_s[wn][lr]=q; }
    }
  }
  __syncthreads();
  if(tid<128){
    float2 pv;
    pv.x = ps_s[0][tid]+ps_s[1][tid];
    pv.y = pq_s[0][tid]+pq_s[1][tid];
    pstats[(size_t)(bm+tid)*250 + (lid>>2)] = pv;
  }
}

// ---------------- energy: reduction-free partial sums ----------------
__global__ __launch_bounds__(256) void k_energy(
  const float* sq1, const float* sq2, const float* sk1, const float* sk2,
  const float* v1p, const float* v2p, float* pene)
{
  int lid = (blockIdx.x&7)*128 + (blockIdx.x>>3);  // bijective, 1024%8==0
  int src = lid>>9, b = (lid>>6)&7, tc = (lid>>4)&3, sc = (lid>>2)&3, eq = lid&3;
  int tid = threadIdx.x;
  const float* SQ = src? sq2:sq1;
  const float* SK = src? sk2:sk1;
  const float* vp = src? v2p:v1p;
  int t0 = tc*16, s0 = sc*32;
  int strow = tid&31, trow = tid>>5;

  __shared__ float sk_lds[32*65];
  float acc_a = 0.f, acc_b = 0.f;
  const float* sqa = SQ + (size_t)(b*64 + t0 + trow)*512;
  const float* sqb = sqa + 8*512;

  for(int ec=eq*2; ec<eq*2+2; ++ec){
    {
      int r = tid>>3, c0 = (tid&7)*8;
      const float* sp = SK + (size_t)(b*128 + s0 + r)*512 + ec*64 + c0;
      float4 A0 = *(const float4*)sp;
      float4 A1 = *(const float4*)(sp+4);
      float* dp = &sk_lds[r*65 + c0];
      dp[0]=A0.x; dp[1]=A0.y; dp[2]=A0.z; dp[3]=A0.w;
      dp[4]=A1.x; dp[5]=A1.y; dp[6]=A1.z; dp[7]=A1.w;
    }
    __syncthreads();
    #pragma unroll
    for(int sub=0; sub<4; ++sub){
      int e0 = ec*64 + sub*16;
      float4 V0 = *(const float4*)(vp+e0),    V1 = *(const float4*)(vp+e0+4);
      float4 V2 = *(const float4*)(vp+e0+8),  V3 = *(const float4*)(vp+e0+12);
      float4 QA0 = *(const float4*)(sqa+e0),  QA1 = *(const float4*)(sqa+e0+4);
      float4 QA2 = *(const float4*)(sqa+e0+8),QA3 = *(const float4*)(sqa+e0+12);
      float4 QB0 = *(const float4*)(sqb+e0),  QB1 = *(const float4*)(sqb+e0+4);
      float4 QB2 = *(const float4*)(sqb+e0+8),QB3 = *(const float4*)(sqb+e0+12);
      float vv[16] = {V0.x,V0.y,V0.z,V0.w,V1.x,V1.y,V1.z,V1.w,V2.x,V2.y,V2.z,V2.w,V3.x,V3.y,V3.z,V3.w};
      float qa[16] = {QA0.x,QA0.y,QA0.z,QA0.w,QA1.x,QA1.y,QA1.z,QA1.w,QA2.x,QA2.y,QA2.z,QA2.w,QA3.x,QA3.y,QA3.z,QA3.w};
      float qb[16] = {QB0.x,QB0.y,QB0.z,QB0.w,QB1.x,QB1.y,QB1.z,QB1.w,QB2.x,QB2.y,QB2.z,QB2.w,QB3.x,QB3.y,QB3.z,QB3.w};
      const float* skr = &sk_lds[strow*65 + sub*16];
      #pragma unroll
      for(int e=0;e<16;++e){
        float skv = skr[e];
        float ya = qa[e] + skv;
        float yb = qb[e] + skv;
        float ra = __builtin_amdgcn_rcpf(__builtin_amdgcn_exp2f(ya) + 1.f);
        float rb = __builtin_amdgcn_rcpf(__builtin_amdgcn_exp2f(yb) + 1.f);
        acc_a = __builtin_fmaf(vv[e], ra, acc_a);
        acc_b = __builtin_fmaf(vv[e], rb, acc_b);
      }
    }
    __syncthreads();
  }
  size_t ia = (size_t)((eq*2+src)*512 + b*64 + t0 + trow)*128 + s0 + strow;
  pene[ia] = acc_a;
  pene[ia + 8*128] = acc_b;
}

// ---------------- softmax + att-LN + weighted sum, block per (src,b,4t) ----------------
__global__ __launch_bounds__(256) void k_sm(
  const float* pene, const float* v1p, const float* v2p,
  const float* k1g, const float* k2g, const float* msk,
  float* al1, float* al2, float* c1, float* c2)
{
  int lid = (blockIdx.x&7)*32 + (blockIdx.x>>3);  // bijective, 256%8==0
  int src = lid>>7, b = (lid>>4)&7, tq = lid&15;
  int tid = threadIdx.x, lane = tid&63, wv = tid>>6;
  int t = tq*4 + wv, bt = b*64 + t;
  const float* vp = src? v2p:v1p;
  const float* kg = src? k2g:k1g;
  float* al = src? al2:al1;
  float* cc = src? c2:c1;
  const float* km_g = msk + 512 + src*1024 + b*128;
  __shared__ float aw_lds[4][132];
  __shared__ float qm_lds[4];

  {
    float vsp = 0.f;
    #pragma unroll
    for(int r2=0;r2<8;++r2) vsp += vp[lane + 64*r2];
    float Vsum = wsum(vsp);
    float qm = msk[bt];
    float km0 = km_g[lane], km1 = km_g[lane+64];
    size_t pbase = (size_t)(src*512 + bt)*128;
    float p0a = pene[pbase + lane]          + pene[pbase + 131072 + lane];
    float p0b = pene[pbase + 262144 + lane] + pene[pbase + 393216 + lane];
    float p1a = pene[pbase + lane + 64]          + pene[pbase + 131072 + lane + 64];
    float p1b = pene[pbase + 262144 + lane + 64] + pene[pbase + 393216 + lane + 64];
    float s0v = Vsum - 2.f*(p0a + p0b);
    float s1v = Vsum - 2.f*(p1a + p1b);
    float a0 = s0v*km0*qm, a1 = s1v*km1*qm;
    float sm = wsum(a0+a1), sqq = wsum(a0*a0+a1*a1);
    float m0 = km0!=0.f ? s0v : -1e30f;
    float m1 = km1!=0.f ? s1v : -1e30f;
    float mx = wmax(fmaxf(m0,m1));
    float e0 = km0!=0.f ? __expf(s0v-mx) : 0.f;
    float e1 = km1!=0.f ? __expf(s1v-mx) : 0.f;
    float den = wsum(e0+e1);
    float mean = sm/128.f;
    float inv  = rsqrtf(sqq/128.f - mean*mean + LNEPS);
    al[(size_t)bt*128 + lane]      = (a0-mean)*inv;
    al[(size_t)bt*128 + lane + 64] = (a1-mean)*inv;
    float rden = 1.f/den;
    aw_lds[wv][lane]      = e0*rden;
    aw_lds[wv][lane+64]   = e1*rden;
    if(lane==0) qm_lds[wv] = qm;
  }
  __syncthreads();
  {
    float acc[4][2] = {};
    const float* kb = kg + (size_t)b*128*512;
    for(int s=0;s<128;++s){
      float kv0 = kb[(size_t)s*512 + tid];
      float kv1 = kb[(size_t)s*512 + tid + 256];
      #pragma unroll
      for(int w=0;w<4;++w){
        float a = aw_lds[w][s];
        acc[w][0] = __builtin_fmaf(a, kv0, acc[w][0]);
        acc[w][1] = __builtin_fmaf(a, kv1, acc[w][1]);
      }
    }
    #pragma unroll
    for(int w=0;w<4;++w){
      float qm = qm_lds[w];
      size_t o = (size_t)(b*64 + tq*4 + w)*512;
      cc[o + tid]       = qm*acc[w][0];
      cc[o + tid + 256] = qm*acc[w][1];
    }
  }
}

// ---------------- out: gate + stats-reduce + LN*p0 + pad + hash-patched store ----------------
__global__ __launch_bounds__(256) void k_out(const u16* logits, const float2* pstats,
    const float* al1, const float* al2, const float* c1, const float* c2,
    const float* tgt, const float* gw, const float* gb,
    const int* map1, const int* map2, float* out)
{
  int row = blockIdx.x>>2, q = blockIdx.x&3, b = row>>6;
  int tid = threadIdx.x, lane = tid&63, wv = tid>>6;
  __shared__ float gred[4][3], rs[4], rq[4], st[2], pl_s[3];
  __shared__ int hkey[1024];
  __shared__ float hval[1024];
  __shared__ unsigned int bmap[252];

  #pragma unroll
  for(int r=0;r<4;++r){ hkey[tid+256*r] = -1; hval[tid+256*r] = 0.f; }
  if(tid < 252) bmap[tid] = 0u;

  {
    float t0v = tgt[(size_t)row*512+tid], t1v = tgt[(size_t)row*512+tid+256];
    float c10 = c1[(size_t)row*512+tid],  c11 = c1[(size_t)row*512+tid+256];
    float c20 = c2[(size_t)row*512+tid],  c21 = c2[(size_t)row*512+tid+256];
    #pragma unroll
    for(int p=0;p<3;++p){
      const float* gp = gw + p*1536;
      float a = gp[tid]*t0v + gp[tid+256]*t1v
              + gp[512+tid]*c10 + gp[768+tid]*c11
              + gp[1024+tid]*c20 + gp[1280+tid]*c21;
      a = wsum(a);
      if(lane==0) gred[wv][p] = a;
    }
  }
  {
    float s=0.f, qv=0.f;
    if(tid < 250){ float2 pv = pstats[(size_t)row*250 + tid]; s = pv.x; qv = pv.y; }
    s = wsum(s); qv = wsum(qv);
    if(lane==0){ rs[wv]=s; rq[wv]=qv; }
  }
  __syncthreads();
  if(tid==0){
    float S = rs[0]+rs[1]+rs[2]+rs[3];
    float Q = rq[0]+rq[1]+rq[2]+rq[3];
    float mean = S/(float)NV;
    float var  = Q/(float)NV - mean*mean;
    st[0] = mean; st[1] = rsqrtf(var+LNEPS);
    float g0 = gred[0][0]+gred[1][0]+gred[2][0]+gred[3][0] + gb[0];
    float g1 = gred[0][1]+gred[1][1]+gred[2][1]+gred[3][1] + gb[1];
    float g2 = gred[0][2]+gred[1][2]+gred[2][2]+gred[3][2] + gb[2];
    float m = fmaxf(g0, fmaxf(g1, g2));
    float e0=__expf(g0-m), e1=__expf(g1-m), e2=__expf(g2-m);
    float sI = 1.f/(e0+e1+e2);
    pl_s[0]=e0*sI; pl_s[1]=e1*sI; pl_s[2]=e2*sI;
  }
  __syncthreads();

  int elo = q*8064;
  {
    int src = tid>>7, sl = tid&127;
    int e = (src ? map2 : map1)[b*128 + sl];
    if(e >= elo && e < elo+8064){
      float val = pl_s[1+src] * (src ? al2 : al1)[(size_t)row*128 + sl];
      unsigned int h = ((unsigned int)e * 2654435761u) >> 22;
      for(;;){
        int old = atomicCAS(&hkey[h], -1, e);
        if(old == -1 || old == e){ atomicAdd(&hval[h], val); break; }
        h = (h+1) & 1023;
      }
      int rel = e - elo;
      atomicOr(&bmap[rel>>5], 1u << (rel&31));
    }
  }
  __syncthreads();

  float mean = st[0], inv = st[1], p0 = pl_s[0];
  const u16* Lr = logits + (size_t)row*NV;
  float* orow = out + (size_t)row*NEXT;
  for(int i=q*2016+tid; i<(q+1)*2016; i+=256){
    int e0 = i*4;
    float4 r;
    if(e0 < NV){
      const u16* L = &Lr[e0];
      r.x = p0*(bf2f(L[0])-mean)*inv;
      r.y = p0*(bf2f(L[1])-mean)*inv;
      r.z = p0*(bf2f(L[2])-mean)*inv;
      r.w = p0*(bf2f(L[3])-mean)*inv;
    } else { r.x=r.y=r.z=r.w=0.f; }
    int rel = e0 - elo;
    unsigned int w4 = (bmap[rel>>5] >> (rel&31)) & 0xFu;
    if(w4){
      #pragma unroll
      for(int j=0;j<4;++j){
        if(w4 & (1u<<j)){
          int e = e0 + j;
          unsigned int h = ((unsigned int)e * 2654435761u) >> 22;
          while(hkey[h] != e) h = (h+1) & 1023;
          float pv = hval[h];
          if(j==0) r.x += pv; else if(j==1) r.y += pv; else if(j==2) r.z += pv; else r.w += pv;
        }
      }
    }
    *(float4*)&orow[e0] = r;
  }
}

extern "C" void kernel_launch(void* const* d_in, const int* in_sizes, int n_in,
                              void* d_out, int out_size, void* d_ws, size_t ws_size,
                              hipStream_t stream)
{
  const float* tgt  = (const float*)d_in[0];
  const float* s1k  = (const float*)d_in[1];
  const float* s2k  = (const float*)d_in[2];
  const int*   map1 = (const int*)d_in[3];
  const int*   map2 = (const int*)d_in[4];
  const float* ofw  = (const float*)d_in[5];
  const float* ofb  = (const float*)d_in[6];
  const float* a1w  = (const float*)d_in[7];
  const float* a1b  = (const float*)d_in[8];
  const float* v1   = (const float*)d_in[9];
  const float* a2w  = (const float*)d_in[10];
  const float* a2b  = (const float*)d_in[11];
  const float* v2   = (const float*)d_in[12];
  const float* gw   = (const float*)d_in[13];
  const float* gb   = (const float*)d_in[14];

  float* wsf   = (float*)d_ws;
  float* sq1   = wsf;                    // 262144
  float* sq2   = wsf + 262144;
  float* sk1   = wsf + 524288;           // 524288
  float* sk2   = wsf + 1048576;
  float* al1   = wsf + 1572864;          // 65536
  float* al2   = wsf + 1638400;
  float* msk   = wsf + 1705984;          // 2560
  float* c1    = wsf + 1709568;          // 262144
  float* c2    = wsf + 1971712;
  float* pene  = wsf + 2233856;          // 524288
  float2* pstats = (float2*)(wsf + 2758144); // 512*250 float2
  u16*  logits = (u16*)(wsf + 3014144);  // 16384000 u16
  u16*  tgtb   = (u16*)(wsf + 11206144);
  u16*  s1b    = (u16*)(wsf + 11337216);
  u16*  s2b    = (u16*)(wsf + 11599360);
  u16*  a1wb   = (u16*)(wsf + 11861504);
  u16*  a2wb   = (u16*)(wsf + 12123648);
  u16*  ofwb   = (u16*)(wsf + 12385792); // 16384000 u16 -> ends ~82 MB
  float* out   = (float*)d_out;

  k_cast   <<<9152, 256, 0, stream>>>(tgt, s1k, s2k, a1w, a2w, ofw, tgtb, s1b, s2b, a1wb, a2wb, ofwb, msk);
  k_proj   <<<dim3(4,8,4), 256, 0, stream>>>(tgtb, s1b, s2b, a1wb, a2wb, a1b, a2b, sq1, sk1, sq2, sk2);
  k_energy <<<1024, 256, 0, stream>>>(sq1, sq2, sk1, sk2, v1, v2, pene);
  k_sm     <<<256, 256, 0, stream>>>(pene, v1, v2, s1k, s2k, msk, al1, al2, c1, c2);
  k_big    <<<1000, 256, 0, stream>>>(tgtb, ofwb, ofb, logits, pstats);
  k_out    <<<2048, 256, 0, stream>>>(logits, pstats, al1, al2, c1, c2, tgt, gw, gb, map1, map2, out);
}

// Round 14
// 119.363 us; speedup vs baseline: 1.3061x; 1.3061x over previous
//
#include <hip/hip_runtime.h>

#define NB 8
#define NT 64
#define NS 128
#define TDIM 512
#define NV 32000
#define NEXT 32256
#define NBT 512
#define LNEPS 1e-5f
#define CLG 2.8853900817779268f  // 2*log2(e)

typedef unsigned short u16;
typedef __attribute__((ext_vector_type(8))) short short8;
typedef __attribute__((ext_vector_type(4))) float f32x4;

__device__ __forceinline__ float bf2f(u16 u){ union{unsigned int i; float f;} v; v.i = ((unsigned int)u)<<16; return v.f; }
__device__ __forceinline__ u16 f2bf(float f){ union{float f; unsigned int i;} v; v.f=f; unsigned int r = v.i + 0x7FFFu + ((v.i>>16)&1u); return (u16)(r>>16); }
__device__ __forceinline__ float wsum(float v){
  v += __shfl_xor(v,32); v += __shfl_xor(v,16); v += __shfl_xor(v,8);
  v += __shfl_xor(v,4);  v += __shfl_xor(v,2);  v += __shfl_xor(v,1); return v; }
__device__ __forceinline__ float wmax(float v){
  v = fmaxf(v,__shfl_xor(v,32)); v = fmaxf(v,__shfl_xor(v,16)); v = fmaxf(v,__shfl_xor(v,8));
  v = fmaxf(v,__shfl_xor(v,4));  v = fmaxf(v,__shfl_xor(v,2));  v = fmaxf(v,__shfl_xor(v,1)); return v; }

#define GL2LDS(gp, lp) __builtin_amdgcn_global_load_lds( \
    (__attribute__((address_space(1))) void*)(void*)(gp), \
    (__attribute__((address_space(3))) void*)(void*)(lp), 16, 0, 0)

// ---------------- f32 -> bf16 cast of ALL GEMM operands + fused masks ----------------
__global__ __launch_bounds__(256) void k_cast(const float* tgt, const float* s1, const float* s2,
    const float* a1w, const float* a2w, const float* ofw,
    u16* tgtb, u16* s1b, u16* s2b, u16* a1wb, u16* a2wb, u16* ofwb, float* msk)
{
  int blk = blockIdx.x;
  const float* src; u16* dst; int base;
  if(blk < 128){       src=tgt; dst=tgtb;  base=blk; }
  else if(blk < 384){  src=s1;  dst=s1b;   base=blk-128; }
  else if(blk < 640){  src=s2;  dst=s2b;   base=blk-384; }
  else if(blk < 896){  src=a1w; dst=a1wb;  base=blk-640; }
  else if(blk < 1152){ src=a2w; dst=a2wb;  base=blk-896; }
  else {               src=ofw; dst=ofwb;  base=blk-1152; }
  size_t off = (size_t)base*2048 + (size_t)threadIdx.x*8;
  float4 x0 = *(const float4*)(src+off);
  float4 x1 = *(const float4*)(src+off+4);
  float xs[8] = {x0.x,x0.y,x0.z,x0.w,x1.x,x1.y,x1.z,x1.w};
  short8 r;
  #pragma unroll
  for(int j=0;j<8;++j) r[j] = (short)f2bf(xs[j]);
  *(short8*)(dst+off) = r;
  if(blk < 640){
    float a = 0.f;
    #pragma unroll
    for(int j=0;j<8;++j) a += fabsf(xs[j]);
    a = wsum(a);
    if((threadIdx.x&63)==0){
      int w = threadIdx.x>>6;
      int midx;
      if(blk<128)      midx = blk*4 + w;
      else if(blk<384) midx = 512 + (blk-128)*4 + w;
      else             midx = 1536 + (blk-384)*4 + w;
      msk[midx] = (a>0.f) ? 1.f : 0.f;
    }
  }
}

// ---------------- MFMA GEMM core (proj path; LDS passed in) ----------------
__device__ __forceinline__ void gemm_core2(u16* Al, u16* Wl, const u16* A, int lda, const u16* W, int ldw,
    float* Cf, int ldc, const float* bias, int K, int bm, int bn, float scale)
{
  const int tid = threadIdx.x, lane = tid&63, wv = tid>>6;
  const int wm = wv>>1, wn = wv&1;
  const int fr = lane&15, fq = lane>>4;
  const int lrow = lane>>2;
  const int lcol = (lane&3)*8;
  f32x4 acc[4][4] = {};
  for(int k0=0;k0<K;k0+=32){
    #pragma unroll
    for(int r=0;r<2;++r){
      int c = wv + 4*r;
      int row = c*16 + lrow;
      const u16* ga = A + (size_t)(bm+row)*lda + k0 + lcol;
      const u16* gw = W + (size_t)(bn+row)*ldw + k0 + lcol;
      GL2LDS(ga, &Al[c*512]);
      GL2LDS(gw, &Wl[c*512]);
    }
    __syncthreads();
    short8 af[4], bfr[4];
    #pragma unroll
    for(int m=0;m<4;++m) af[m] = *(const short8*)&Al[(wm*64 + m*16 + fr)*32 + fq*8];
    #pragma unroll
    for(int n=0;n<4;++n) bfr[n] = *(const short8*)&Wl[(wn*64 + n*16 + fr)*32 + fq*8];
    #pragma unroll
    for(int m=0;m<4;++m)
      #pragma unroll
      for(int n=0;n<4;++n)
        acc[m][n] = __builtin_amdgcn_mfma_f32_16x16x32_bf16(af[m], bfr[n], acc[m][n], 0,0,0);
    __syncthreads();
  }
  #pragma unroll
  for(int m=0;m<4;++m)
    #pragma unroll
    for(int n=0;n<4;++n)
      #pragma unroll
      for(int i=0;i<4;++i){
        int row = bm + wm*64 + m*16 + fq*4 + i;
        int col = bn + wn*64 + n*16 + fr;
        float bv = bias ? bias[col] : 0.f;
        Cf[(size_t)row*ldc + col] = (acc[m][n][i] + bv)*scale;
      }
}

// ---------------- k_bigproj: blocks <1000 = big GEMM; 1000..1127 = proj tasks ----------------
__global__ __launch_bounds__(256) void k_bigproj(const u16* A, const u16* W, const float* bias,
    u16* logits, float2* pstats,
    const u16* s1, const u16* s2, const u16* w1, const u16* w2,
    const float* b1, const float* b2,
    float* sq1, float* sk1, float* sq2, float* sk2)
{
  __shared__ u16 Al[128*32];
  __shared__ u16 Wl[128*32];
  __shared__ float ps_s[2][128], pq_s[2][128];
  __shared__ u16 c16[2][16][136];

  if(blockIdx.x >= 1000){
    int p = blockIdx.x - 1000;           // 0..127
    int z = p>>5, y = (p>>2)&7, x = p&3;
    int Mt = (z&1) ? 1024 : 512;
    int bm = y*128; if(bm >= Mt) return;
    const u16* Ap = (z&1) ? ((z>>1) ? s2 : s1) : A;
    const u16* Wp = ((z>>1) ? w2 : w1) + ((z&1) ? TDIM : 0);
    float* Cf = (z==0) ? sq1 : (z==1) ? sk1 : (z==2) ? sq2 : sk2;
    const float* bp = (z&1) ? nullptr : ((z>>1) ? b2 : b1);
    gemm_core2(Al, Wl, Ap, TDIM, Wp, 2*TDIM, Cf, TDIM, bp, TDIM, bm, x*128, CLG);
    return;
  }

  int lid = (blockIdx.x&7)*125 + (blockIdx.x>>3);
  int bm = (lid&3)*128, bn = (lid>>2)*128;
  const int tid = threadIdx.x, lane = tid&63, wv = tid>>6;
  const int wm = wv>>1, wn = wv&1;
  const int fr = lane&15, fq = lane>>4;
  const int lrow = lane>>2;
  const int lcol = (lane&3)*8;
  f32x4 acc[4][4] = {};
  for(int k0=0;k0<512;k0+=32){
    #pragma unroll
    for(int r=0;r<2;++r){
      int c = wv + 4*r;
      int row = c*16 + lrow;
      GL2LDS(A + (size_t)(bm+row)*512 + k0 + lcol, &Al[c*512]);
      GL2LDS(W + (size_t)(bn+row)*512 + k0 + lcol, &Wl[c*512]);
    }
    __syncthreads();
    short8 af[4], bfr[4];
    #pragma unroll
    for(int m=0;m<4;++m) af[m] = *(const short8*)&Al[(wm*64 + m*16 + fr)*32 + fq*8];
    #pragma unroll
    for(int n=0;n<4;++n) bfr[n] = *(const short8*)&Wl[(wn*64 + n*16 + fr)*32 + fq*8];
    #pragma unroll
    for(int m=0;m<4;++m)
      #pragma unroll
      for(int n=0;n<4;++n)
        acc[m][n] = __builtin_amdgcn_mfma_f32_16x16x32_bf16(af[m], bfr[n], acc[m][n], 0,0,0);
    __syncthreads();
  }

  // epilogue: per m-chunk, stats partials + LDS-staged coalesced bf16 store
  #pragma unroll
  for(int m=0;m<4;++m){
    float rs_[4]={0,0,0,0}, rq_[4]={0,0,0,0};
    #pragma unroll
    for(int n=0;n<4;++n)
      #pragma unroll
      for(int i=0;i<4;++i){
        int col = bn + wn*64 + n*16 + fr;
        float v = acc[m][n][i] + bias[col];
        c16[wm][fq*4+i][wn*64 + n*16 + fr] = f2bf(v);
        rs_[i] += v; rq_[i] += v*v;
      }
    #pragma unroll
    for(int i=0;i<4;++i){
      float a=rs_[i], q=rq_[i];
      a+=__shfl_xor(a,1); a+=__shfl_xor(a,2); a+=__shfl_xor(a,4); a+=__shfl_xor(a,8);
      q+=__shfl_xor(q,1); q+=__shfl_xor(q,2); q+=__shfl_xor(q,4); q+=__shfl_xor(q,8);
      if(fr==0){ int lr = wm*64 + m*16 + fq*4 + i; ps_s[wn][lr]=a; pq_s[wn][lr]=q; }
    }
    __syncthreads();
    {
      int band = tid>>7, r = (tid>>3)&15, c0 = (tid&7)*16;
      int grow = bm + band*64 + m*16 + r;
      short8 o0 = *(const short8*)&c16[band][r][c0];
      short8 o1 = *(const short8*)&c16[band][r][c0+8];
      *(short8*)&logits[(size_t)grow*NV + bn + c0]     = o0;
      *(short8*)&logits[(size_t)grow*NV + bn + c0 + 8] = o1;
    }
    __syncthreads();
  }
  if(tid<128){
    float2 pv;
    pv.x = ps_s[0][tid]+ps_s[1][tid];
    pv.y = pq_s[0][tid]+pq_s[1][tid];
    pstats[(size_t)(bm+tid)*250 + (lid>>2)] = pv;
  }
}

// ---------------- energy: reduction-free partial sums ----------------
__global__ __launch_bounds__(256) void k_energy(
  const float* sq1, const float* sq2, const float* sk1, const float* sk2,
  const float* v1p, const float* v2p, float* pene)
{
  int lid = (blockIdx.x&7)*128 + (blockIdx.x>>3);  // bijective, 1024%8==0
  int src = lid>>9, b = (lid>>6)&7, tc = (lid>>4)&3, sc = (lid>>2)&3, eq = lid&3;
  int tid = threadIdx.x;
  const float* SQ = src? sq2:sq1;
  const float* SK = src? sk2:sk1;
  const float* vp = src? v2p:v1p;
  int t0 = tc*16, s0 = sc*32;
  int strow = tid&31, trow = tid>>5;

  __shared__ float sk_lds[32*65];
  float acc_a = 0.f, acc_b = 0.f;
  const float* sqa = SQ + (size_t)(b*64 + t0 + trow)*512;
  const float* sqb = sqa + 8*512;

  for(int ec=eq*2; ec<eq*2+2; ++ec){
    {
      int r = tid>>3, c0 = (tid&7)*8;
      const float* sp = SK + (size_t)(b*128 + s0 + r)*512 + ec*64 + c0;
      float4 A0 = *(const float4*)sp;
      float4 A1 = *(const float4*)(sp+4);
      float* dp = &sk_lds[r*65 + c0];
      dp[0]=A0.x; dp[1]=A0.y; dp[2]=A0.z; dp[3]=A0.w;
      dp[4]=A1.x; dp[5]=A1.y; dp[6]=A1.z; dp[7]=A1.w;
    }
    __syncthreads();
    #pragma unroll
    for(int sub=0; sub<4; ++sub){
      int e0 = ec*64 + sub*16;
      float4 V0 = *(const float4*)(vp+e0),    V1 = *(const float4*)(vp+e0+4);
      float4 V2 = *(const float4*)(vp+e0+8),  V3 = *(const float4*)(vp+e0+12);
      float4 QA0 = *(const float4*)(sqa+e0),  QA1 = *(const float4*)(sqa+e0+4);
      float4 QA2 = *(const float4*)(sqa+e0+8),QA3 = *(const float4*)(sqa+e0+12);
      float4 QB0 = *(const float4*)(sqb+e0),  QB1 = *(const float4*)(sqb+e0+4);
      float4 QB2 = *(const float4*)(sqb+e0+8),QB3 = *(const float4*)(sqb+e0+12);
      float vv[16] = {V0.x,V0.y,V0.z,V0.w,V1.x,V1.y,V1.z,V1.w,V2.x,V2.y,V2.z,V2.w,V3.x,V3.y,V3.z,V3.w};
      float qa[16] = {QA0.x,QA0.y,QA0.z,QA0.w,QA1.x,QA1.y,QA1.z,QA1.w,QA2.x,QA2.y,QA2.z,QA2.w,QA3.x,QA3.y,QA3.z,QA3.w};
      float qb[16] = {QB0.x,QB0.y,QB0.z,QB0.w,QB1.x,QB1.y,QB1.z,QB1.w,QB2.x,QB2.y,QB2.z,QB2.w,QB3.x,QB3.y,QB3.z,QB3.w};
      const float* skr = &sk_lds[strow*65 + sub*16];
      #pragma unroll
      for(int e=0;e<16;++e){
        float skv = skr[e];
        float ya = qa[e] + skv;
        float yb = qb[e] + skv;
        float ra = __builtin_amdgcn_rcpf(__builtin_amdgcn_exp2f(ya) + 1.f);
        float rb = __builtin_amdgcn_rcpf(__builtin_amdgcn_exp2f(yb) + 1.f);
        acc_a = __builtin_fmaf(vv[e], ra, acc_a);
        acc_b = __builtin_fmaf(vv[e], rb, acc_b);
      }
    }
    __syncthreads();
  }
  size_t ia = (size_t)((eq*2+src)*512 + b*64 + t0 + trow)*128 + s0 + strow;
  pene[ia] = acc_a;
  pene[ia + 8*128] = acc_b;
}

// ---------------- softmax + att-LN + weighted sum, block per (src,b,4t) ----------------
__global__ __launch_bounds__(256) void k_sm(
  const float* pene, const float* v1p, const float* v2p,
  const float* k1g, const float* k2g, const float* msk,
  float* al1, float* al2, float* c1, float* c2)
{
  int lid = (blockIdx.x&7)*32 + (blockIdx.x>>3);  // bijective, 256%8==0
  int src = lid>>7, b = (lid>>4)&7, tq = lid&15;
  int tid = threadIdx.x, lane = tid&63, wv = tid>>6;
  int t = tq*4 + wv, bt = b*64 + t;
  const float* vp = src? v2p:v1p;
  const float* kg = src? k2g:k1g;
  float* al = src? al2:al1;
  float* cc = src? c2:c1;
  const float* km_g = msk + 512 + src*1024 + b*128;
  __shared__ float aw_lds[4][132];
  __shared__ float qm_lds[4];

  {
    float vsp = 0.f;
    #pragma unroll
    for(int r2=0;r2<8;++r2) vsp += vp[lane + 64*r2];
    float Vsum = wsum(vsp);
    float qm = msk[bt];
    float km0 = km_g[lane], km1 = km_g[lane+64];
    size_t pbase = (size_t)(src*512 + bt)*128;
    float p0a = pene[pbase + lane]          + pene[pbase + 131072 + lane];
    float p0b = pene[pbase + 262144 + lane] + pene[pbase + 393216 + lane];
    float p1a = pene[pbase + lane + 64]          + pene[pbase + 131072 + lane + 64];
    float p1b = pene[pbase + 262144 + lane + 64] + pene[pbase + 393216 + lane + 64];
    float s0v = Vsum - 2.f*(p0a + p0b);
    float s1v = Vsum - 2.f*(p1a + p1b);
    float a0 = s0v*km0*qm, a1 = s1v*km1*qm;
    float sm = wsum(a0+a1), sqq = wsum(a0*a0+a1*a1);
    float m0 = km0!=0.f ? s0v : -1e30f;
    float m1 = km1!=0.f ? s1v : -1e30f;
    float mx = wmax(fmaxf(m0,m1));
    float e0 = km0!=0.f ? __expf(s0v-mx) : 0.f;
    float e1 = km1!=0.f ? __expf(s1v-mx) : 0.f;
    float den = wsum(e0+e1);
    float mean = sm/128.f;
    float inv  = rsqrtf(sqq/128.f - mean*mean + LNEPS);
    al[(size_t)bt*128 + lane]      = (a0-mean)*inv;
    al[(size_t)bt*128 + lane + 64] = (a1-mean)*inv;
    float rden = 1.f/den;
    aw_lds[wv][lane]      = e0*rden;
    aw_lds[wv][lane+64]   = e1*rden;
    if(lane==0) qm_lds[wv] = qm;
  }
  __syncthreads();
  {
    float acc[4][2] = {};
    const float* kb = kg + (size_t)b*128*512;
    for(int s=0;s<128;++s){
      float kv0 = kb[(size_t)s*512 + tid];
      float kv1 = kb[(size_t)s*512 + tid + 256];
      #pragma unroll
      for(int w=0;w<4;++w){
        float a = aw_lds[w][s];
        acc[w][0] = __builtin_fmaf(a, kv0, acc[w][0]);
        acc[w][1] = __builtin_fmaf(a, kv1, acc[w][1]);
      }
    }
    #pragma unroll
    for(int w=0;w<4;++w){
      float qm = qm_lds[w];
      size_t o = (size_t)(b*64 + tq*4 + w)*512;
      cc[o + tid]       = qm*acc[w][0];
      cc[o + tid + 256] = qm*acc[w][1];
    }
  }
}

// ---------------- out: gate + stats-reduce + LN*p0 + pad + hash-patched store ----------------
__global__ __launch_bounds__(256) void k_out(const u16* logits, const float2* pstats,
    const float* al1, const float* al2, const float* c1, const float* c2,
    const float* tgt, const float* gw, const float* gb,
    const int* map1, const int* map2, float* out)
{
  int row = blockIdx.x>>2, q = blockIdx.x&3, b = row>>6;
  int tid = threadIdx.x, lane = tid&63, wv = tid>>6;
  __shared__ float gred[4][3], rs[4], rq[4], st[2], pl_s[3];
  __shared__ int hkey[1024];
  __shared__ float hval[1024];
  __shared__ unsigned int bmap[252];

  #pragma unroll
  for(int r=0;r<4;++r){ hkey[tid+256*r] = -1; hval[tid+256*r] = 0.f; }
  if(tid < 252) bmap[tid] = 0u;

  {
    float t0v = tgt[(size_t)row*512+tid], t1v = tgt[(size_t)row*512+tid+256];
    float c10 = c1[(size_t)row*512+tid],  c11 = c1[(size_t)row*512+tid+256];
    float c20 = c2[(size_t)row*512+tid],  c21 = c2[(size_t)row*512+tid+256];
    #pragma unroll
    for(int p=0;p<3;++p){
      const float* gp = gw + p*1536;
      float a = gp[tid]*t0v + gp[tid+256]*t1v
              + gp[512+tid]*c10 + gp[768+tid]*c11
              + gp[1024+tid]*c20 + gp[1280+tid]*c21;
      a = wsum(a);
      if(lane==0) gred[wv][p] = a;
    }
  }
  {
    float s=0.f, qv=0.f;
    if(tid < 250){ float2 pv = pstats[(size_t)row*250 + tid]; s = pv.x; qv = pv.y; }
    s = wsum(s); qv = wsum(qv);
    if(lane==0){ rs[wv]=s; rq[wv]=qv; }
  }
  __syncthreads();
  if(tid==0){
    float S = rs[0]+rs[1]+rs[2]+rs[3];
    float Q = rq[0]+rq[1]+rq[2]+rq[3];
    float mean = S/(float)NV;
    float var  = Q/(float)NV - mean*mean;
    st[0] = mean; st[1] = rsqrtf(var+LNEPS);
    float g0 = gred[0][0]+gred[1][0]+gred[2][0]+gred[3][0] + gb[0];
    float g1 = gred[0][1]+gred[1][1]+gred[2][1]+gred[3][1] + gb[1];
    float g2 = gred[0][2]+gred[1][2]+gred[2][2]+gred[3][2] + gb[2];
    float m = fmaxf(g0, fmaxf(g1, g2));
    float e0=__expf(g0-m), e1=__expf(g1-m), e2=__expf(g2-m);
    float sI = 1.f/(e0+e1+e2);
    pl_s[0]=e0*sI; pl_s[1]=e1*sI; pl_s[2]=e2*sI;
  }
  __syncthreads();

  int elo = q*8064;
  {
    int src = tid>>7, sl = tid&127;
    int e = (src ? map2 : map1)[b*128 + sl];
    if(e >= elo && e < elo+8064){
      float val = pl_s[1+src] * (src ? al2 : al1)[(size_t)row*128 + sl];
      unsigned int h = ((unsigned int)e * 2654435761u) >> 22;
      for(;;){
        int old = atomicCAS(&hkey[h], -1, e);
        if(old == -1 || old == e){ atomicAdd(&hval[h], val); break; }
        h = (h+1) & 1023;
      }
      int rel = e - elo;
      atomicOr(&bmap[rel>>5], 1u << (rel&31));
    }
  }
  __syncthreads();

  float mean = st[0], inv = st[1], p0 = pl_s[0];
  const u16* Lr = logits + (size_t)row*NV;
  float* orow = out + (size_t)row*NEXT;
  for(int i=q*2016+tid; i<(q+1)*2016; i+=256){
    int e0 = i*4;
    float4 r;
    if(e0 < NV){
      const u16* L = &Lr[e0];
      r.x = p0*(bf2f(L[0])-mean)*inv;
      r.y = p0*(bf2f(L[1])-mean)*inv;
      r.z = p0*(bf2f(L[2])-mean)*inv;
      r.w = p0*(bf2f(L[3])-mean)*inv;
    } else { r.x=r.y=r.z=r.w=0.f; }
    int rel = e0 - elo;
    unsigned int w4 = (bmap[rel>>5] >> (rel&31)) & 0xFu;
    if(w4){
      #pragma unroll
      for(int j=0;j<4;++j){
        if(w4 & (1u<<j)){
          int e = e0 + j;
          unsigned int h = ((unsigned int)e * 2654435761u) >> 22;
          while(hkey[h] != e) h = (h+1) & 1023;
          float pv = hval[h];
          if(j==0) r.x += pv; else if(j==1) r.y += pv; else if(j==2) r.z += pv; else r.w += pv;
        }
      }
    }
    *(float4*)&orow[e0] = r;
  }
}

extern "C" void kernel_launch(void* const* d_in, const int* in_sizes, int n_in,
                              void* d_out, int out_size, void* d_ws, size_t ws_size,
                              hipStream_t stream)
{
  const float* tgt  = (const float*)d_in[0];
  const float* s1k  = (const float*)d_in[1];
  const float* s2k  = (const float*)d_in[2];
  const int*   map1 = (const int*)d_in[3];
  const int*   map2 = (const int*)d_in[4];
  const float* ofw  = (const float*)d_in[5];
  const float* ofb  = (const float*)d_in[6];
  const float* a1w  = (const float*)d_in[7];
  const float* a1b  = (const float*)d_in[8];
  const float* v1   = (const float*)d_in[9];
  const float* a2w  = (const float*)d_in[10];
  const float* a2b  = (const float*)d_in[11];
  const float* v2   = (const float*)d_in[12];
  const float* gw   = (const float*)d_in[13];
  const float* gb   = (const float*)d_in[14];

  float* wsf   = (float*)d_ws;
  float* sq1   = wsf;                    // 262144
  float* sq2   = wsf + 262144;
  float* sk1   = wsf + 524288;           // 524288
  float* sk2   = wsf + 1048576;
  float* al1   = wsf + 1572864;          // 65536
  float* al2   = wsf + 1638400;
  float* msk   = wsf + 1705984;          // 2560
  float* c1    = wsf + 1709568;          // 262144
  float* c2    = wsf + 1971712;
  float* pene  = wsf + 2233856;          // 524288
  float2* pstats = (float2*)(wsf + 2758144); // 512*250 float2
  u16*  logits = (u16*)(wsf + 3014144);  // 16384000 u16
  u16*  tgtb   = (u16*)(wsf + 11206144);
  u16*  s1b    = (u16*)(wsf + 11337216);
  u16*  s2b    = (u16*)(wsf + 11599360);
  u16*  a1wb   = (u16*)(wsf + 11861504);
  u16*  a2wb   = (u16*)(wsf + 12123648);
  u16*  ofwb   = (u16*)(wsf + 12385792); // 16384000 u16 -> ends ~82 MB
  float* out   = (float*)d_out;

  k_cast   <<<9152, 256, 0, stream>>>(tgt, s1k, s2k, a1w, a2w, ofw, tgtb, s1b, s2b, a1wb, a2wb, ofwb, msk);
  k_bigproj<<<1128, 256, 0, stream>>>(tgtb, ofwb, ofb, logits, pstats,
                                      s1b, s2b, a1wb, a2wb, a1b, a2b, sq1, sk1, sq2, sk2);
  k_energy <<<1024, 256, 0, stream>>>(sq1, sq2, sk1, sk2, v1, v2, pene);
  k_sm     <<<256, 256, 0, stream>>>(pene, v1, v2, s1k, s2k, msk, al1, al2, c1, c2);
  k_out    <<<2048, 256, 0, stream>>>(logits, pstats, al1, al2, c1, c2, tgt, gw, gb, map1, map2, out);
}

// Round 15
// 114.474 us; speedup vs baseline: 1.3619x; 1.0427x over previous
//
#include <hip/hip_runtime.h>

#define NB 8
#define NT 64
#define NS 128
#define TDIM 512
#define NV 32000
#define NEXT 32256
#define NBT 512
#define LNEPS 1e-5f
#define CLG 2.8853900817779268f  // 2*log2(e)

typedef unsigned short u16;
typedef __attribute__((ext_vector_type(8))) short short8;
typedef __attribute__((ext_vector_type(4))) float f32x4;

__device__ __forceinline__ float bf2f(u16 u){ union{unsigned int i; float f;} v; v.i = ((unsigned int)u)<<16; return v.f; }
__device__ __forceinline__ u16 f2bf(float f){ union{float f; unsigned int i;} v; v.f=f; unsigned int r = v.i + 0x7FFFu + ((v.i>>16)&1u); return (u16)(r>>16); }
__device__ __forceinline__ float wsum(float v){
  v += __shfl_xor(v,32); v += __shfl_xor(v,16); v += __shfl_xor(v,8);
  v += __shfl_xor(v,4);  v += __shfl_xor(v,2);  v += __shfl_xor(v,1); return v; }
__device__ __forceinline__ float wmax(float v){
  v = fmaxf(v,__shfl_xor(v,32)); v = fmaxf(v,__shfl_xor(v,16)); v = fmaxf(v,__shfl_xor(v,8));
  v = fmaxf(v,__shfl_xor(v,4));  v = fmaxf(v,__shfl_xor(v,2));  v = fmaxf(v,__shfl_xor(v,1)); return v; }

#define GL2LDS(gp, lp) __builtin_amdgcn_global_load_lds( \
    (__attribute__((address_space(1))) void*)(void*)(gp), \
    (__attribute__((address_space(3))) void*)(void*)(lp), 16, 0, 0)

// ---------------- f32 -> bf16 cast of ALL GEMM operands + fused masks ----------------
__global__ __launch_bounds__(256) void k_cast(const float* tgt, const float* s1, const float* s2,
    const float* a1w, const float* a2w, const float* ofw,
    u16* tgtb, u16* s1b, u16* s2b, u16* a1wb, u16* a2wb, u16* ofwb, float* msk)
{
  int blk = blockIdx.x;
  const float* src; u16* dst; int base;
  if(blk < 128){       src=tgt; dst=tgtb;  base=blk; }
  else if(blk < 384){  src=s1;  dst=s1b;   base=blk-128; }
  else if(blk < 640){  src=s2;  dst=s2b;   base=blk-384; }
  else if(blk < 896){  src=a1w; dst=a1wb;  base=blk-640; }
  else if(blk < 1152){ src=a2w; dst=a2wb;  base=blk-896; }
  else {               src=ofw; dst=ofwb;  base=blk-1152; }
  size_t off = (size_t)base*2048 + (size_t)threadIdx.x*8;
  float4 x0 = *(const float4*)(src+off);
  float4 x1 = *(const float4*)(src+off+4);
  float xs[8] = {x0.x,x0.y,x0.z,x0.w,x1.x,x1.y,x1.z,x1.w};
  short8 r;
  #pragma unroll
  for(int j=0;j<8;++j) r[j] = (short)f2bf(xs[j]);
  *(short8*)(dst+off) = r;
  if(blk < 640){
    float a = 0.f;
    #pragma unroll
    for(int j=0;j<8;++j) a += fabsf(xs[j]);
    a = wsum(a);
    if((threadIdx.x&63)==0){
      int w = threadIdx.x>>6;
      int midx;
      if(blk<128)      midx = blk*4 + w;
      else if(blk<384) midx = 512 + (blk-128)*4 + w;
      else             midx = 1536 + (blk-384)*4 + w;
      msk[midx] = (a>0.f) ? 1.f : 0.f;
    }
  }
}

// ---------------- MFMA GEMM core (proj path; LDS passed in) ----------------
__device__ __forceinline__ void gemm_core2(u16* Al, u16* Wl, const u16* A, int lda, const u16* W, int ldw,
    float* Cf, int ldc, const float* bias, int K, int bm, int bn, float scale)
{
  const int tid = threadIdx.x, lane = tid&63, wv = tid>>6;
  const int wm = wv>>1, wn = wv&1;
  const int fr = lane&15, fq = lane>>4;
  const int lrow = lane>>2;
  const int lcol = (lane&3)*8;
  f32x4 acc[4][4] = {};
  for(int k0=0;k0<K;k0+=32){
    #pragma unroll
    for(int r=0;r<2;++r){
      int c = wv + 4*r;
      int row = c*16 + lrow;
      const u16* ga = A + (size_t)(bm+row)*lda + k0 + lcol;
      const u16* gw = W + (size_t)(bn+row)*ldw + k0 + lcol;
      GL2LDS(ga, &Al[c*512]);
      GL2LDS(gw, &Wl[c*512]);
    }
    __syncthreads();
    short8 af[4], bfr[4];
    #pragma unroll
    for(int m=0;m<4;++m) af[m] = *(const short8*)&Al[(wm*64 + m*16 + fr)*32 + fq*8];
    #pragma unroll
    for(int n=0;n<4;++n) bfr[n] = *(const short8*)&Wl[(wn*64 + n*16 + fr)*32 + fq*8];
    #pragma unroll
    for(int m=0;m<4;++m)
      #pragma unroll
      for(int n=0;n<4;++n)
        acc[m][n] = __builtin_amdgcn_mfma_f32_16x16x32_bf16(af[m], bfr[n], acc[m][n], 0,0,0);
    __syncthreads();
  }
  #pragma unroll
  for(int m=0;m<4;++m)
    #pragma unroll
    for(int n=0;n<4;++n)
      #pragma unroll
      for(int i=0;i<4;++i){
        int row = bm + wm*64 + m*16 + fq*4 + i;
        int col = bn + wn*64 + n*16 + fr;
        float bv = bias ? bias[col] : 0.f;
        Cf[(size_t)row*ldc + col] = (acc[m][n][i] + bv)*scale;
      }
}

// ---------------- k_bigproj: blocks <2000 = big GEMM (64x128 tiles); 2000..2127 = proj ----------------
__global__ __launch_bounds__(256) void k_bigproj(const u16* A, const u16* W, const float* bias,
    u16* logits, float2* pstats,
    const u16* s1, const u16* s2, const u16* w1, const u16* w2,
    const float* b1, const float* b2,
    float* sq1, float* sk1, float* sq2, float* sk2)
{
  __shared__ u16 Al[128*32];      // big: W-tile (8KB) | proj: A-tile
  __shared__ u16 Wl[128*32];      // big: A-tile (first 4KB) | proj: W-tile
  __shared__ float ps_s[2][64], pq_s[2][64];

  if(blockIdx.x >= 2000){
    int p = blockIdx.x - 2000;           // 0..127
    int z = p>>5, y = (p>>2)&7, x = p&3;
    int Mt = (z&1) ? 1024 : 512;
    int bm = y*128; if(bm >= Mt) return;
    const u16* Ap = (z&1) ? ((z>>1) ? s2 : s1) : A;
    const u16* Wp = ((z>>1) ? w2 : w1) + ((z&1) ? TDIM : 0);
    float* Cf = (z==0) ? sq1 : (z==1) ? sk1 : (z==2) ? sq2 : sk2;
    const float* bp = (z&1) ? nullptr : ((z>>1) ? b2 : b1);
    gemm_core2(Al, Wl, Ap, TDIM, Wp, 2*TDIM, Cf, TDIM, bp, TDIM, bm, x*128, CLG);
    return;
  }

  // big path: 64x128 tile, 4 waves (2x2), wave tile 32x64, acc[2][4]
  int lid = (blockIdx.x&7)*250 + (blockIdx.x>>3);   // bijective (2000%8==0)
  int bm = (lid&7)*64, bn = (lid>>3)*128, nb = lid>>3;
  const int tid = threadIdx.x, lane = tid&63, wv = tid>>6;
  const int wm = wv>>1, wn = wv&1;
  const int fr = lane&15, fq = lane>>4;
  const int lrow = lane>>2;
  const int lcol = (lane&3)*8;
  f32x4 acc[2][4] = {};
  for(int k0=0;k0<512;k0+=32){
    // A: 64 rows, 4 chunks of 16 rows (one per wave)
    GL2LDS(A + (size_t)(bm + wv*16 + lrow)*512 + k0 + lcol, &Wl[wv*512]);
    // W: 128 rows, 8 chunks
    #pragma unroll
    for(int r=0;r<2;++r){
      int c = wv + 4*r;
      GL2LDS(W + (size_t)(bn + c*16 + lrow)*512 + k0 + lcol, &Al[c*512]);
    }
    __syncthreads();
    short8 af[2], bfr[4];
    #pragma unroll
    for(int m=0;m<2;++m) af[m] = *(const short8*)&Wl[(wm*32 + m*16 + fr)*32 + fq*8];
    #pragma unroll
    for(int n=0;n<4;++n) bfr[n] = *(const short8*)&Al[(wn*64 + n*16 + fr)*32 + fq*8];
    #pragma unroll
    for(int m=0;m<2;++m)
      #pragma unroll
      for(int n=0;n<4;++n)
        acc[m][n] = __builtin_amdgcn_mfma_f32_16x16x32_bf16(af[m], bfr[n], acc[m][n], 0,0,0);
    __syncthreads();
  }

  // epilogue: direct bf16 stores + row sum/sumsq partials
  #pragma unroll
  for(int m=0;m<2;++m){
    float rs_[4]={0,0,0,0}, rq_[4]={0,0,0,0};
    #pragma unroll
    for(int n=0;n<4;++n)
      #pragma unroll
      for(int i=0;i<4;++i){
        int row = bm + wm*32 + m*16 + fq*4 + i;
        int col = bn + wn*64 + n*16 + fr;
        float v = acc[m][n][i] + bias[col];
        logits[(size_t)row*NV + col] = f2bf(v);
        rs_[i] += v; rq_[i] += v*v;
      }
    #pragma unroll
    for(int i=0;i<4;++i){
      float a=rs_[i], q=rq_[i];
      a+=__shfl_xor(a,1); a+=__shfl_xor(a,2); a+=__shfl_xor(a,4); a+=__shfl_xor(a,8);
      q+=__shfl_xor(q,1); q+=__shfl_xor(q,2); q+=__shfl_xor(q,4); q+=__shfl_xor(q,8);
      if(fr==0){ int lr = wm*32 + m*16 + fq*4 + i; ps_s[wn][lr]=a; pq_s[wn][lr]=q; }
    }
  }
  __syncthreads();
  if(tid<64){
    float2 pv;
    pv.x = ps_s[0][tid]+ps_s[1][tid];
    pv.y = pq_s[0][tid]+pq_s[1][tid];
    pstats[(size_t)(bm+tid)*250 + nb] = pv;
  }
}

// ---------------- energy: reduction-free partial sums ----------------
__global__ __launch_bounds__(256) void k_energy(
  const float* sq1, const float* sq2, const float* sk1, const float* sk2,
  const float* v1p, const float* v2p, float* pene)
{
  int lid = (blockIdx.x&7)*128 + (blockIdx.x>>3);  // bijective, 1024%8==0
  int src = lid>>9, b = (lid>>6)&7, tc = (lid>>4)&3, sc = (lid>>2)&3, eq = lid&3;
  int tid = threadIdx.x;
  const float* SQ = src? sq2:sq1;
  const float* SK = src? sk2:sk1;
  const float* vp = src? v2p:v1p;
  int t0 = tc*16, s0 = sc*32;
  int strow = tid&31, trow = tid>>5;

  __shared__ float sk_lds[32*65];
  float acc_a = 0.f, acc_b = 0.f;
  const float* sqa = SQ + (size_t)(b*64 + t0 + trow)*512;
  const float* sqb = sqa + 8*512;

  for(int ec=eq*2; ec<eq*2+2; ++ec){
    {
      int r = tid>>3, c0 = (tid&7)*8;
      const float* sp = SK + (size_t)(b*128 + s0 + r)*512 + ec*64 + c0;
      float4 A0 = *(const float4*)sp;
      float4 A1 = *(const float4*)(sp+4);
      float* dp = &sk_lds[r*65 + c0];
      dp[0]=A0.x; dp[1]=A0.y; dp[2]=A0.z; dp[3]=A0.w;
      dp[4]=A1.x; dp[5]=A1.y; dp[6]=A1.z; dp[7]=A1.w;
    }
    __syncthreads();
    #pragma unroll
    for(int sub=0; sub<4; ++sub){
      int e0 = ec*64 + sub*16;
      float4 V0 = *(const float4*)(vp+e0),    V1 = *(const float4*)(vp+e0+4);
      float4 V2 = *(const float4*)(vp+e0+8),  V3 = *(const float4*)(vp+e0+12);
      float4 QA0 = *(const float4*)(sqa+e0),  QA1 = *(const float4*)(sqa+e0+4);
      float4 QA2 = *(const float4*)(sqa+e0+8),QA3 = *(const float4*)(sqa+e0+12);
      float4 QB0 = *(const float4*)(sqb+e0),  QB1 = *(const float4*)(sqb+e0+4);
      float4 QB2 = *(const float4*)(sqb+e0+8),QB3 = *(const float4*)(sqb+e0+12);
      float vv[16] = {V0.x,V0.y,V0.z,V0.w,V1.x,V1.y,V1.z,V1.w,V2.x,V2.y,V2.z,V2.w,V3.x,V3.y,V3.z,V3.w};
      float qa[16] = {QA0.x,QA0.y,QA0.z,QA0.w,QA1.x,QA1.y,QA1.z,QA1.w,QA2.x,QA2.y,QA2.z,QA2.w,QA3.x,QA3.y,QA3.z,QA3.w};
      float qb[16] = {QB0.x,QB0.y,QB0.z,QB0.w,QB1.x,QB1.y,QB1.z,QB1.w,QB2.x,QB2.y,QB2.z,QB2.w,QB3.x,QB3.y,QB3.z,QB3.w};
      const float* skr = &sk_lds[strow*65 + sub*16];
      #pragma unroll
      for(int e=0;e<16;++e){
        float skv = skr[e];
        float ya = qa[e] + skv;
        float yb = qb[e] + skv;
        float ra = __builtin_amdgcn_rcpf(__builtin_amdgcn_exp2f(ya) + 1.f);
        float rb = __builtin_amdgcn_rcpf(__builtin_amdgcn_exp2f(yb) + 1.f);
        acc_a = __builtin_fmaf(vv[e], ra, acc_a);
        acc_b = __builtin_fmaf(vv[e], rb, acc_b);
      }
    }
    __syncthreads();
  }
  size_t ia = (size_t)((eq*2+src)*512 + b*64 + t0 + trow)*128 + s0 + strow;
  pene[ia] = acc_a;
  pene[ia + 8*128] = acc_b;
}

// ---------------- softmax + att-LN + weighted sum, block per (src,b,4t) ----------------
__global__ __launch_bounds__(256) void k_sm(
  const float* pene, const float* v1p, const float* v2p,
  const float* k1g, const float* k2g, const float* msk,
  float* al1, float* al2, float* c1, float* c2)
{
  int lid = (blockIdx.x&7)*32 + (blockIdx.x>>3);  // bijective, 256%8==0
  int src = lid>>7, b = (lid>>4)&7, tq = lid&15;
  int tid = threadIdx.x, lane = tid&63, wv = tid>>6;
  int t = tq*4 + wv, bt = b*64 + t;
  const float* vp = src? v2p:v1p;
  const float* kg = src? k2g:k1g;
  float* al = src? al2:al1;
  float* cc = src? c2:c1;
  const float* km_g = msk + 512 + src*1024 + b*128;
  __shared__ float aw_lds[4][132];
  __shared__ float qm_lds[4];

  {
    float vsp = 0.f;
    #pragma unroll
    for(int r2=0;r2<8;++r2) vsp += vp[lane + 64*r2];
    float Vsum = wsum(vsp);
    float qm = msk[bt];
    float km0 = km_g[lane], km1 = km_g[lane+64];
    size_t pbase = (size_t)(src*512 + bt)*128;
    float p0a = pene[pbase + lane]          + pene[pbase + 131072 + lane];
    float p0b = pene[pbase + 262144 + lane] + pene[pbase + 393216 + lane];
    float p1a = pene[pbase + lane + 64]          + pene[pbase + 131072 + lane + 64];
    float p1b = pene[pbase + 262144 + lane + 64] + pene[pbase + 393216 + lane + 64];
    float s0v = Vsum - 2.f*(p0a + p0b);
    float s1v = Vsum - 2.f*(p1a + p1b);
    float a0 = s0v*km0*qm, a1 = s1v*km1*qm;
    float sm = wsum(a0+a1), sqq = wsum(a0*a0+a1*a1);
    float m0 = km0!=0.f ? s0v : -1e30f;
    float m1 = km1!=0.f ? s1v : -1e30f;
    float mx = wmax(fmaxf(m0,m1));
    float e0 = km0!=0.f ? __expf(s0v-mx) : 0.f;
    float e1 = km1!=0.f ? __expf(s1v-mx) : 0.f;
    float den = wsum(e0+e1);
    float mean = sm/128.f;
    float inv  = rsqrtf(sqq/128.f - mean*mean + LNEPS);
    al[(size_t)bt*128 + lane]      = (a0-mean)*inv;
    al[(size_t)bt*128 + lane + 64] = (a1-mean)*inv;
    float rden = 1.f/den;
    aw_lds[wv][lane]      = e0*rden;
    aw_lds[wv][lane+64]   = e1*rden;
    if(lane==0) qm_lds[wv] = qm;
  }
  __syncthreads();
  {
    float acc[4][2] = {};
    const float* kb = kg + (size_t)b*128*512;
    for(int s=0;s<128;++s){
      float kv0 = kb[(size_t)s*512 + tid];
      float kv1 = kb[(size_t)s*512 + tid + 256];
      #pragma unroll
      for(int w=0;w<4;++w){
        float a = aw_lds[w][s];
        acc[w][0] = __builtin_fmaf(a, kv0, acc[w][0]);
        acc[w][1] = __builtin_fmaf(a, kv1, acc[w][1]);
      }
    }
    #pragma unroll
    for(int w=0;w<4;++w){
      float qm = qm_lds[w];
      size_t o = (size_t)(b*64 + tq*4 + w)*512;
      cc[o + tid]       = qm*acc[w][0];
      cc[o + tid + 256] = qm*acc[w][1];
    }
  }
}

// ---------------- out: gate + stats-reduce + LN*p0 + pad + hash-patched store ----------------
__global__ __launch_bounds__(256) void k_out(const u16* logits, const float2* pstats,
    const float* al1, const float* al2, const float* c1, const float* c2,
    const float* tgt, const float* gw, const float* gb,
    const int* map1, const int* map2, float* out)
{
  int row = blockIdx.x>>2, q = blockIdx.x&3, b = row>>6;
  int tid = threadIdx.x, lane = tid&63, wv = tid>>6;
  __shared__ float gred[4][3], rs[4], rq[4], st[2], pl_s[3];
  __shared__ int hkey[1024];
  __shared__ float hval[1024];
  __shared__ unsigned int bmap[252];

  #pragma unroll
  for(int r=0;r<4;++r){ hkey[tid+256*r] = -1; hval[tid+256*r] = 0.f; }
  if(tid < 252) bmap[tid] = 0u;

  {
    float t0v = tgt[(size_t)row*512+tid], t1v = tgt[(size_t)row*512+tid+256];
    float c10 = c1[(size_t)row*512+tid],  c11 = c1[(size_t)row*512+tid+256];
    float c20 = c2[(size_t)row*512+tid],  c21 = c2[(size_t)row*512+tid+256];
    #pragma unroll
    for(int p=0;p<3;++p){
      const float* gp = gw + p*1536;
      float a = gp[tid]*t0v + gp[tid+256]*t1v
              + gp[512+tid]*c10 + gp[768+tid]*c11
              + gp[1024+tid]*c20 + gp[1280+tid]*c21;
      a = wsum(a);
      if(lane==0) gred[wv][p] = a;
    }
  }
  {
    float s=0.f, qv=0.f;
    if(tid < 250){ float2 pv = pstats[(size_t)row*250 + tid]; s = pv.x; qv = pv.y; }
    s = wsum(s); qv = wsum(qv);
    if(lane==0){ rs[wv]=s; rq[wv]=qv; }
  }
  __syncthreads();
  if(tid==0){
    float S = rs[0]+rs[1]+rs[2]+rs[3];
    float Q = rq[0]+rq[1]+rq[2]+rq[3];
    float mean = S/(float)NV;
    float var  = Q/(float)NV - mean*mean;
    st[0] = mean; st[1] = rsqrtf(var+LNEPS);
    float g0 = gred[0][0]+gred[1][0]+gred[2][0]+gred[3][0] + gb[0];
    float g1 = gred[0][1]+gred[1][1]+gred[2][1]+gred[3][1] + gb[1];
    float g2 = gred[0][2]+gred[1][2]+gred[2][2]+gred[3][2] + gb[2];
    float m = fmaxf(g0, fmaxf(g1, g2));
    float e0=__expf(g0-m), e1=__expf(g1-m), e2=__expf(g2-m);
    float sI = 1.f/(e0+e1+e2);
    pl_s[0]=e0*sI; pl_s[1]=e1*sI; pl_s[2]=e2*sI;
  }
  __syncthreads();

  int elo = q*8064;
  {
    int src = tid>>7, sl = tid&127;
    int e = (src ? map2 : map1)[b*128 + sl];
    if(e >= elo && e < elo+8064){
      float val = pl_s[1+src] * (src ? al2 : al1)[(size_t)row*128 + sl];
      unsigned int h = ((unsigned int)e * 2654435761u) >> 22;
      for(;;){
        int old = atomicCAS(&hkey[h], -1, e);
        if(old == -1 || old == e){ atomicAdd(&hval[h], val); break; }
        h = (h+1) & 1023;
      }
      int rel = e - elo;
      atomicOr(&bmap[rel>>5], 1u << (rel&31));
    }
  }
  __syncthreads();

  float mean = st[0], inv = st[1], p0 = pl_s[0];
  const u16* Lr = logits + (size_t)row*NV;
  float* orow = out + (size_t)row*NEXT;
  for(int i=q*2016+tid; i<(q+1)*2016; i+=256){
    int e0 = i*4;
    float4 r;
    if(e0 < NV){
      const u16* L = &Lr[e0];
      r.x = p0*(bf2f(L[0])-mean)*inv;
      r.y = p0*(bf2f(L[1])-mean)*inv;
      r.z = p0*(bf2f(L[2])-mean)*inv;
      r.w = p0*(bf2f(L[3])-mean)*inv;
    } else { r.x=r.y=r.z=r.w=0.f; }
    int rel = e0 - elo;
    unsigned int w4 = (bmap[rel>>5] >> (rel&31)) & 0xFu;
    if(w4){
      #pragma unroll
      for(int j=0;j<4;++j){
        if(w4 & (1u<<j)){
          int e = e0 + j;
          unsigned int h = ((unsigned int)e * 2654435761u) >> 22;
          while(hkey[h] != e) h = (h+1) & 1023;
          float pv = hval[h];
          if(j==0) r.x += pv; else if(j==1) r.y += pv; else if(j==2) r.z += pv; else r.w += pv;
        }
      }
    }
    *(float4*)&orow[e0] = r;
  }
}

extern "C" void kernel_launch(void* const* d_in, const int* in_sizes, int n_in,
                              void* d_out, int out_size, void* d_ws, size_t ws_size,
                              hipStream_t stream)
{
  const float* tgt  = (const float*)d_in[0];
  const float* s1k  = (const float*)d_in[1];
  const float* s2k  = (const float*)d_in[2];
  const int*   map1 = (const int*)d_in[3];
  const int*   map2 = (const int*)d_in[4];
  const float* ofw  = (const float*)d_in[5];
  const float* ofb  = (const float*)d_in[6];
  const float* a1w  = (const float*)d_in[7];
  const float* a1b  = (const float*)d_in[8];
  const float* v1   = (const float*)d_in[9];
  const float* a2w  = (const float*)d_in[10];
  const float* a2b  = (const float*)d_in[11];
  const float* v2   = (const float*)d_in[12];
  const float* gw   = (const float*)d_in[13];
  const float* gb   = (const float*)d_in[14];

  float* wsf   = (float*)d_ws;
  float* sq1   = wsf;                    // 262144
  float* sq2   = wsf + 262144;
  float* sk1   = wsf + 524288;           // 524288
  float* sk2   = wsf + 1048576;
  float* al1   = wsf + 1572864;          // 65536
  float* al2   = wsf + 1638400;
  float* msk   = wsf + 1705984;          // 2560
  float* c1    = wsf + 1709568;          // 262144
  float* c2    = wsf + 1971712;
  float* pene  = wsf + 2233856;          // 524288
  float2* pstats = (float2*)(wsf + 2758144); // 512*250 float2
  u16*  logits = (u16*)(wsf + 3014144);  // 16384000 u16
  u16*  tgtb   = (u16*)(wsf + 11206144);
  u16*  s1b    = (u16*)(wsf + 11337216);
  u16*  s2b    = (u16*)(wsf + 11599360);
  u16*  a1wb   = (u16*)(wsf + 11861504);
  u16*  a2wb   = (u16*)(wsf + 12123648);
  u16*  ofwb   = (u16*)(wsf + 12385792); // 16384000 u16 -> ends ~82 MB
  float* out   = (float*)d_out;

  k_cast   <<<9152, 256, 0, stream>>>(tgt, s1k, s2k, a1w, a2w, ofw, tgtb, s1b, s2b, a1wb, a2wb, ofwb, msk);
  k_bigproj<<<2128, 256, 0, stream>>>(tgtb, ofwb, ofb, logits, pstats,
                                      s1b, s2b, a1wb, a2wb, a1b, a2b, sq1, sk1, sq2, sk2);
  k_energy <<<1024, 256, 0, stream>>>(sq1, sq2, sk1, sk2, v1, v2, pene);
  k_sm     <<<256, 256, 0, stream>>>(pene, v1, v2, s1k, s2k, msk, al1, al2, c1, c2);
  k_out    <<<2048, 256, 0, stream>>>(logits, pstats, al1, al2, c1, c2, tgt, gw, gb, map1, map2, out);
}

// Round 16
// 114.341 us; speedup vs baseline: 1.3635x; 1.0012x over previous
//
#include <hip/hip_runtime.h>

#define NB 8
#define NT 64
#define NS 128
#define TDIM 512
#define NV 32000
#define NEXT 32256
#define NBT 512
#define LNEPS 1e-5f
#define CLG 2.8853900817779268f  // 2*log2(e)

typedef unsigned short u16;
typedef __attribute__((ext_vector_type(8))) short short8;
typedef __attribute__((ext_vector_type(4))) float f32x4;

__device__ __forceinline__ float bf2f(u16 u){ union{unsigned int i; float f;} v; v.i = ((unsigned int)u)<<16; return v.f; }
__device__ __forceinline__ u16 f2bf(float f){ union{float f; unsigned int i;} v; v.f=f; unsigned int r = v.i + 0x7FFFu + ((v.i>>16)&1u); return (u16)(r>>16); }
__device__ __forceinline__ float wsum(float v){
  v += __shfl_xor(v,32); v += __shfl_xor(v,16); v += __shfl_xor(v,8);
  v += __shfl_xor(v,4);  v += __shfl_xor(v,2);  v += __shfl_xor(v,1); return v; }
__device__ __forceinline__ float wmax(float v){
  v = fmaxf(v,__shfl_xor(v,32)); v = fmaxf(v,__shfl_xor(v,16)); v = fmaxf(v,__shfl_xor(v,8));
  v = fmaxf(v,__shfl_xor(v,4));  v = fmaxf(v,__shfl_xor(v,2));  v = fmaxf(v,__shfl_xor(v,1)); return v; }

#define GL2LDS(gp, lp) __builtin_amdgcn_global_load_lds( \
    (__attribute__((address_space(1))) void*)(void*)(gp), \
    (__attribute__((address_space(3))) void*)(void*)(lp), 16, 0, 0)

// ---------------- stage 1: f32->bf16 cast of SMALL operands + fused masks ----------------
__global__ __launch_bounds__(256) void k_cast_small(const float* tgt, const float* s1, const float* s2,
    const float* a1w, const float* a2w,
    u16* tgtb, u16* s1b, u16* s2b, u16* a1wb, u16* a2wb, float* msk)
{
  int blk = blockIdx.x;
  const float* src; u16* dst; int base;
  if(blk < 128){       src=tgt; dst=tgtb;  base=blk; }
  else if(blk < 384){  src=s1;  dst=s1b;   base=blk-128; }
  else if(blk < 640){  src=s2;  dst=s2b;   base=blk-384; }
  else if(blk < 896){  src=a1w; dst=a1wb;  base=blk-640; }
  else {               src=a2w; dst=a2wb;  base=blk-896; }
  size_t off = (size_t)base*2048 + (size_t)threadIdx.x*8;
  float4 x0 = *(const float4*)(src+off);
  float4 x1 = *(const float4*)(src+off+4);
  float xs[8] = {x0.x,x0.y,x0.z,x0.w,x1.x,x1.y,x1.z,x1.w};
  short8 r;
  #pragma unroll
  for(int j=0;j<8;++j) r[j] = (short)f2bf(xs[j]);
  *(short8*)(dst+off) = r;
  if(blk < 640){
    float a = 0.f;
    #pragma unroll
    for(int j=0;j<8;++j) a += fabsf(xs[j]);
    a = wsum(a);
    if((threadIdx.x&63)==0){
      int w = threadIdx.x>>6;
      int midx;
      if(blk<128)      midx = blk*4 + w;
      else if(blk<384) midx = 512 + (blk-128)*4 + w;
      else             midx = 1536 + (blk-384)*4 + w;
      msk[midx] = (a>0.f) ? 1.f : 0.f;
    }
  }
}

// ---------------- MFMA GEMM core (proj path; LDS passed in) ----------------
__device__ __forceinline__ void gemm_core2(u16* Al, u16* Wl, const u16* A, int lda, const u16* W, int ldw,
    float* Cf, int ldc, const float* bias, int K, int bm, int bn, float scale)
{
  const int tid = threadIdx.x, lane = tid&63, wv = tid>>6;
  const int wm = wv>>1, wn = wv&1;
  const int fr = lane&15, fq = lane>>4;
  const int lrow = lane>>2;
  const int lcol = (lane&3)*8;
  f32x4 acc[4][4] = {};
  for(int k0=0;k0<K;k0+=32){
    #pragma unroll
    for(int r=0;r<2;++r){
      int c = wv + 4*r;
      int row = c*16 + lrow;
      const u16* ga = A + (size_t)(bm+row)*lda + k0 + lcol;
      const u16* gw = W + (size_t)(bn+row)*ldw + k0 + lcol;
      GL2LDS(ga, &Al[c*512]);
      GL2LDS(gw, &Wl[c*512]);
    }
    __syncthreads();
    short8 af[4], bfr[4];
    #pragma unroll
    for(int m=0;m<4;++m) af[m] = *(const short8*)&Al[(wm*64 + m*16 + fr)*32 + fq*8];
    #pragma unroll
    for(int n=0;n<4;++n) bfr[n] = *(const short8*)&Wl[(wn*64 + n*16 + fr)*32 + fq*8];
    #pragma unroll
    for(int m=0;m<4;++m)
      #pragma unroll
      for(int n=0;n<4;++n)
        acc[m][n] = __builtin_amdgcn_mfma_f32_16x16x32_bf16(af[m], bfr[n], acc[m][n], 0,0,0);
    __syncthreads();
  }
  #pragma unroll
  for(int m=0;m<4;++m)
    #pragma unroll
    for(int n=0;n<4;++n)
      #pragma unroll
      for(int i=0;i<4;++i){
        int row = bm + wm*64 + m*16 + fq*4 + i;
        int col = bn + wn*64 + n*16 + fr;
        float bv = bias ? bias[col] : 0.f;
        Cf[(size_t)row*ldc + col] = (acc[m][n][i] + bv)*scale;
      }
}

// ---------------- stage 2: proj GEMM (blocks 0..127) + ofw cast (blocks 128..8127) ----------------
__global__ __launch_bounds__(256) void k_projcast(
    const u16* tgtb, const u16* s1, const u16* s2, const u16* w1, const u16* w2,
    const float* b1, const float* b2,
    float* sq1, float* sk1, float* sq2, float* sk2,
    const float* ofw, u16* ofwb)
{
  __shared__ u16 Al[128*32];
  __shared__ u16 Wl[128*32];
  if(blockIdx.x < 128){
    int p = blockIdx.x;
    int z = p>>5, y = (p>>2)&7, x = p&3;
    int Mt = (z&1) ? 1024 : 512;
    int bm = y*128; if(bm >= Mt) return;
    const u16* Ap = (z&1) ? ((z>>1) ? s2 : s1) : tgtb;
    const u16* Wp = ((z>>1) ? w2 : w1) + ((z&1) ? TDIM : 0);
    float* Cf = (z==0) ? sq1 : (z==1) ? sk1 : (z==2) ? sq2 : sk2;
    const float* bp = (z&1) ? nullptr : ((z>>1) ? b2 : b1);
    gemm_core2(Al, Wl, Ap, TDIM, Wp, 2*TDIM, Cf, TDIM, bp, TDIM, bm, x*128, CLG);
    return;
  }
  size_t off = (size_t)(blockIdx.x-128)*2048 + (size_t)threadIdx.x*8;
  float4 x0 = *(const float4*)(ofw+off);
  float4 x1 = *(const float4*)(ofw+off+4);
  float xs[8] = {x0.x,x0.y,x0.z,x0.w,x1.x,x1.y,x1.z,x1.w};
  short8 r;
  #pragma unroll
  for(int j=0;j<8;++j) r[j] = (short)f2bf(xs[j]);
  *(short8*)(ofwb+off) = r;
}

// ---------------- stage 3: big GEMM (blocks 0..1999, 64x128 tiles) + energy (2000..3023) ----------------
__global__ __launch_bounds__(256) void k_bigen(const u16* A, const u16* W, const float* bias,
    u16* logits, float2* pstats,
    const float* sq1, const float* sq2, const float* sk1, const float* sk2,
    const float* v1p, const float* v2p, float* pene)
{
  union __align__(16) SMem {
    struct { u16 Wt[128*32]; u16 At[64*32]; float ps[2][64]; float pq[2][64]; } big;
    float sk[32*65];
  };
  __shared__ SMem smem;
  const int tid = threadIdx.x, lane = tid&63, wv = tid>>6;

  if(blockIdx.x < 2000){
    // big path: 64x128 tile, 4 waves (2x2), wave tile 32x64, acc[2][4]
    int lid = (blockIdx.x&7)*250 + (blockIdx.x>>3);   // bijective (2000%8==0)
    int bm = (lid&7)*64, bn = (lid>>3)*128, nb = lid>>3;
    const int wm = wv>>1, wn = wv&1;
    const int fr = lane&15, fq = lane>>4;
    const int lrow = lane>>2;
    const int lcol = (lane&3)*8;
    f32x4 acc[2][4] = {};
    for(int k0=0;k0<512;k0+=32){
      GL2LDS(A + (size_t)(bm + wv*16 + lrow)*512 + k0 + lcol, &smem.big.At[wv*512]);
      #pragma unroll
      for(int r=0;r<2;++r){
        int c = wv + 4*r;
        GL2LDS(W + (size_t)(bn + c*16 + lrow)*512 + k0 + lcol, &smem.big.Wt[c*512]);
      }
      __syncthreads();
      short8 af[2], bfr[4];
      #pragma unroll
      for(int m=0;m<2;++m) af[m] = *(const short8*)&smem.big.At[(wm*32 + m*16 + fr)*32 + fq*8];
      #pragma unroll
      for(int n=0;n<4;++n) bfr[n] = *(const short8*)&smem.big.Wt[(wn*64 + n*16 + fr)*32 + fq*8];
      #pragma unroll
      for(int m=0;m<2;++m)
        #pragma unroll
        for(int n=0;n<4;++n)
          acc[m][n] = __builtin_amdgcn_mfma_f32_16x16x32_bf16(af[m], bfr[n], acc[m][n], 0,0,0);
      __syncthreads();
    }
    #pragma unroll
    for(int m=0;m<2;++m){
      float rs_[4]={0,0,0,0}, rq_[4]={0,0,0,0};
      #pragma unroll
      for(int n=0;n<4;++n)
        #pragma unroll
        for(int i=0;i<4;++i){
          int row = bm + wm*32 + m*16 + fq*4 + i;
          int col = bn + wn*64 + n*16 + fr;
          float v = acc[m][n][i] + bias[col];
          logits[(size_t)row*NV + col] = f2bf(v);
          rs_[i] += v; rq_[i] += v*v;
        }
      #pragma unroll
      for(int i=0;i<4;++i){
        float a=rs_[i], q=rq_[i];
        a+=__shfl_xor(a,1); a+=__shfl_xor(a,2); a+=__shfl_xor(a,4); a+=__shfl_xor(a,8);
        q+=__shfl_xor(q,1); q+=__shfl_xor(q,2); q+=__shfl_xor(q,4); q+=__shfl_xor(q,8);
        if(fr==0){ int lr = wm*32 + m*16 + fq*4 + i; smem.big.ps[wn][lr]=a; smem.big.pq[wn][lr]=q; }
      }
    }
    __syncthreads();
    if(tid<64){
      float2 pv;
      pv.x = smem.big.ps[0][tid]+smem.big.ps[1][tid];
      pv.y = smem.big.pq[0][tid]+smem.big.pq[1][tid];
      pstats[(size_t)(bm+tid)*250 + nb] = pv;
    }
    return;
  }

  // energy path
  int id = blockIdx.x - 2000;
  int lid = (id&7)*128 + (id>>3);  // bijective, 1024%8==0
  int src = lid>>9, b = (lid>>6)&7, tc = (lid>>4)&3, sc = (lid>>2)&3, eq = lid&3;
  const float* SQ = src? sq2:sq1;
  const float* SK = src? sk2:sk1;
  const float* vp = src? v2p:v1p;
  int t0 = tc*16, s0 = sc*32;
  int strow = tid&31, trow = tid>>5;

  float acc_a = 0.f, acc_b = 0.f;
  const float* sqa = SQ + (size_t)(b*64 + t0 + trow)*512;
  const float* sqb = sqa + 8*512;

  for(int ec=eq*2; ec<eq*2+2; ++ec){
    {
      int r = tid>>3, c0 = (tid&7)*8;
      const float* sp = SK + (size_t)(b*128 + s0 + r)*512 + ec*64 + c0;
      float4 A0 = *(const float4*)sp;
      float4 A1 = *(const float4*)(sp+4);
      float* dp = &smem.sk[r*65 + c0];
      dp[0]=A0.x; dp[1]=A0.y; dp[2]=A0.z; dp[3]=A0.w;
      dp[4]=A1.x; dp[5]=A1.y; dp[6]=A1.z; dp[7]=A1.w;
    }
    __syncthreads();
    #pragma unroll
    for(int sub=0; sub<4; ++sub){
      int e0 = ec*64 + sub*16;
      float4 V0 = *(const float4*)(vp+e0),    V1 = *(const float4*)(vp+e0+4);
      float4 V2 = *(const float4*)(vp+e0+8),  V3 = *(const float4*)(vp+e0+12);
      float4 QA0 = *(const float4*)(sqa+e0),  QA1 = *(const float4*)(sqa+e0+4);
      float4 QA2 = *(const float4*)(sqa+e0+8),QA3 = *(const float4*)(sqa+e0+12);
      float4 QB0 = *(const float4*)(sqb+e0),  QB1 = *(const float4*)(sqb+e0+4);
      float4 QB2 = *(const float4*)(sqb+e0+8),QB3 = *(const float4*)(sqb+e0+12);
      float vv[16] = {V0.x,V0.y,V0.z,V0.w,V1.x,V1.y,V1.z,V1.w,V2.x,V2.y,V2.z,V2.w,V3.x,V3.y,V3.z,V3.w};
      float qa[16] = {QA0.x,QA0.y,QA0.z,QA0.w,QA1.x,QA1.y,QA1.z,QA1.w,QA2.x,QA2.y,QA2.z,QA2.w,QA3.x,QA3.y,QA3.z,QA3.w};
      float qb[16] = {QB0.x,QB0.y,QB0.z,QB0.w,QB1.x,QB1.y,QB1.z,QB1.w,QB2.x,QB2.y,QB2.z,QB2.w,QB3.x,QB3.y,QB3.z,QB3.w};
      const float* skr = &smem.sk[strow*65 + sub*16];
      #pragma unroll
      for(int e=0;e<16;++e){
        float skv = skr[e];
        float ya = qa[e] + skv;
        float yb = qb[e] + skv;
        float ra = __builtin_amdgcn_rcpf(__builtin_amdgcn_exp2f(ya) + 1.f);
        float rb = __builtin_amdgcn_rcpf(__builtin_amdgcn_exp2f(yb) + 1.f);
        acc_a = __builtin_fmaf(vv[e], ra, acc_a);
        acc_b = __builtin_fmaf(vv[e], rb, acc_b);
      }
    }
    __syncthreads();
  }
  size_t ia = (size_t)((eq*2+src)*512 + b*64 + t0 + trow)*128 + s0 + strow;
  pene[ia] = acc_a;
  pene[ia + 8*128] = acc_b;
}

// ---------------- softmax + att-LN + weighted sum, block per (src,b,4t) ----------------
__global__ __launch_bounds__(256) void k_sm(
  const float* pene, const float* v1p, const float* v2p,
  const float* k1g, const float* k2g, const float* msk,
  float* al1, float* al2, float* c1, float* c2)
{
  int lid = (blockIdx.x&7)*32 + (blockIdx.x>>3);  // bijective, 256%8==0
  int src = lid>>7, b = (lid>>4)&7, tq = lid&15;
  int tid = threadIdx.x, lane = tid&63, wv = tid>>6;
  int t = tq*4 + wv, bt = b*64 + t;
  const float* vp = src? v2p:v1p;
  const float* kg = src? k2g:k1g;
  float* al = src? al2:al1;
  float* cc = src? c2:c1;
  const float* km_g = msk + 512 + src*1024 + b*128;
  __shared__ float aw_lds[4][132];
  __shared__ float qm_lds[4];

  {
    float vsp = 0.f;
    #pragma unroll
    for(int r2=0;r2<8;++r2) vsp += vp[lane + 64*r2];
    float Vsum = wsum(vsp);
    float qm = msk[bt];
    float km0 = km_g[lane], km1 = km_g[lane+64];
    size_t pbase = (size_t)(src*512 + bt)*128;
    float p0a = pene[pbase + lane]          + pene[pbase + 131072 + lane];
    float p0b = pene[pbase + 262144 + lane] + pene[pbase + 393216 + lane];
    float p1a = pene[pbase + lane + 64]          + pene[pbase + 131072 + lane + 64];
    float p1b = pene[pbase + 262144 + lane + 64] + pene[pbase + 393216 + lane + 64];
    float s0v = Vsum - 2.f*(p0a + p0b);
    float s1v = Vsum - 2.f*(p1a + p1b);
    float a0 = s0v*km0*qm, a1 = s1v*km1*qm;
    float sm = wsum(a0+a1), sqq = wsum(a0*a0+a1*a1);
    float m0 = km0!=0.f ? s0v : -1e30f;
    float m1 = km1!=0.f ? s1v : -1e30f;
    float mx = wmax(fmaxf(m0,m1));
    float e0 = km0!=0.f ? __expf(s0v-mx) : 0.f;
    float e1 = km1!=0.f ? __expf(s1v-mx) : 0.f;
    float den = wsum(e0+e1);
    float mean = sm/128.f;
    float inv  = rsqrtf(sqq/128.f - mean*mean + LNEPS);
    al[(size_t)bt*128 + lane]      = (a0-mean)*inv;
    al[(size_t)bt*128 + lane + 64] = (a1-mean)*inv;
    float rden = 1.f/den;
    aw_lds[wv][lane]      = e0*rden;
    aw_lds[wv][lane+64]   = e1*rden;
    if(lane==0) qm_lds[wv] = qm;
  }
  __syncthreads();
  {
    float acc[4][2] = {};
    const float* kb = kg + (size_t)b*128*512;
    for(int s=0;s<128;++s){
      float kv0 = kb[(size_t)s*512 + tid];
      float kv1 = kb[(size_t)s*512 + tid + 256];
      #pragma unroll
      for(int w=0;w<4;++w){
        float a = aw_lds[w][s];
        acc[w][0] = __builtin_fmaf(a, kv0, acc[w][0]);
        acc[w][1] = __builtin_fmaf(a, kv1, acc[w][1]);
      }
    }
    #pragma unroll
    for(int w=0;w<4;++w){
      float qm = qm_lds[w];
      size_t o = (size_t)(b*64 + tq*4 + w)*512;
      cc[o + tid]       = qm*acc[w][0];
      cc[o + tid + 256] = qm*acc[w][1];
    }
  }
}

// ---------------- out: gate + stats-reduce + LN*p0 + pad + hash-patched store ----------------
__global__ __launch_bounds__(256) void k_out(const u16* logits, const float2* pstats,
    const float* al1, const float* al2, const float* c1, const float* c2,
    const float* tgt, const float* gw, const float* gb,
    const int* map1, const int* map2, float* out)
{
  int row = blockIdx.x>>2, q = blockIdx.x&3, b = row>>6;
  int tid = threadIdx.x, lane = tid&63, wv = tid>>6;
  __shared__ float gred[4][3], rs[4], rq[4], st[2], pl_s[3];
  __shared__ int hkey[1024];
  __shared__ float hval[1024];
  __shared__ unsigned int bmap[252];

  #pragma unroll
  for(int r=0;r<4;++r){ hkey[tid+256*r] = -1; hval[tid+256*r] = 0.f; }
  if(tid < 252) bmap[tid] = 0u;

  {
    float t0v = tgt[(size_t)row*512+tid], t1v = tgt[(size_t)row*512+tid+256];
    float c10 = c1[(size_t)row*512+tid],  c11 = c1[(size_t)row*512+tid+256];
    float c20 = c2[(size_t)row*512+tid],  c21 = c2[(size_t)row*512+tid+256];
    #pragma unroll
    for(int p=0;p<3;++p){
      const float* gp = gw + p*1536;
      float a = gp[tid]*t0v + gp[tid+256]*t1v
              + gp[512+tid]*c10 + gp[768+tid]*c11
              + gp[1024+tid]*c20 + gp[1280+tid]*c21;
      a = wsum(a);
      if(lane==0) gred[wv][p] = a;
    }
  }
  {
    float s=0.f, qv=0.f;
    if(tid < 250){ float2 pv = pstats[(size_t)row*250 + tid]; s = pv.x; qv = pv.y; }
    s = wsum(s); qv = wsum(qv);
    if(lane==0){ rs[wv]=s; rq[wv]=qv; }
  }
  __syncthreads();
  if(tid==0){
    float S = rs[0]+rs[1]+rs[2]+rs[3];
    float Q = rq[0]+rq[1]+rq[2]+rq[3];
    float mean = S/(float)NV;
    float var  = Q/(float)NV - mean*mean;
    st[0] = mean; st[1] = rsqrtf(var+LNEPS);
    float g0 = gred[0][0]+gred[1][0]+gred[2][0]+gred[3][0] + gb[0];
    float g1 = gred[0][1]+gred[1][1]+gred[2][1]+gred[3][1] + gb[1];
    float g2 = gred[0][2]+gred[1][2]+gred[2][2]+gred[3][2] + gb[2];
    float m = fmaxf(g0, fmaxf(g1, g2));
    float e0=__expf(g0-m), e1=__expf(g1-m), e2=__expf(g2-m);
    float sI = 1.f/(e0+e1+e2);
    pl_s[0]=e0*sI; pl_s[1]=e1*sI; pl_s[2]=e2*sI;
  }
  __syncthreads();

  int elo = q*8064;
  {
    int src = tid>>7, sl = tid&127;
    int e = (src ? map2 : map1)[b*128 + sl];
    if(e >= elo && e < elo+8064){
      float val = pl_s[1+src] * (src ? al2 : al1)[(size_t)row*128 + sl];
      unsigned int h = ((unsigned int)e * 2654435761u) >> 22;
      for(;;){
        int old = atomicCAS(&hkey[h], -1, e);
        if(old == -1 || old == e){ atomicAdd(&hval[h], val); break; }
        h = (h+1) & 1023;
      }
      int rel = e - elo;
      atomicOr(&bmap[rel>>5], 1u << (rel&31));
    }
  }
  __syncthreads();

  float mean = st[0], inv = st[1], p0 = pl_s[0];
  const u16* Lr = logits + (size_t)row*NV;
  float* orow = out + (size_t)row*NEXT;
  for(int i=q*2016+tid; i<(q+1)*2016; i+=256){
    int e0 = i*4;
    float4 r;
    if(e0 < NV){
      const u16* L = &Lr[e0];
      r.x = p0*(bf2f(L[0])-mean)*inv;
      r.y = p0*(bf2f(L[1])-mean)*inv;
      r.z = p0*(bf2f(L[2])-mean)*inv;
      r.w = p0*(bf2f(L[3])-mean)*inv;
    } else { r.x=r.y=r.z=r.w=0.f; }
    int rel = e0 - elo;
    unsigned int w4 = (bmap[rel>>5] >> (rel&31)) & 0xFu;
    if(w4){
      #pragma unroll
      for(int j=0;j<4;++j){
        if(w4 & (1u<<j)){
          int e = e0 + j;
          unsigned int h = ((unsigned int)e * 2654435761u) >> 22;
          while(hkey[h] != e) h = (h+1) & 1023;
          float pv = hval[h];
          if(j==0) r.x += pv; else if(j==1) r.y += pv; else if(j==2) r.z += pv; else r.w += pv;
        }
      }
    }
    *(float4*)&orow[e0] = r;
  }
}

extern "C" void kernel_launch(void* const* d_in, const int* in_sizes, int n_in,
                              void* d_out, int out_size, void* d_ws, size_t ws_size,
                              hipStream_t stream)
{
  const float* tgt  = (const float*)d_in[0];
  const float* s1k  = (const float*)d_in[1];
  const float* s2k  = (const float*)d_in[2];
  const int*   map1 = (const int*)d_in[3];
  const int*   map2 = (const int*)d_in[4];
  const float* ofw  = (const float*)d_in[5];
  const float* ofb  = (const float*)d_in[6];
  const float* a1w  = (const float*)d_in[7];
  const float* a1b  = (const float*)d_in[8];
  const float* v1   = (const float*)d_in[9];
  const float* a2w  = (const float*)d_in[10];
  const float* a2b  = (const float*)d_in[11];
  const float* v2   = (const float*)d_in[12];
  const float* gw   = (const float*)d_in[13];
  const float* gb   = (const float*)d_in[14];

  float* wsf   = (float*)d_ws;
  float* sq1   = wsf;                    // 262144
  float* sq2   = wsf + 262144;
  float* sk1   = wsf + 524288;           // 524288
  float* sk2   = wsf + 1048576;
  float* al1   = wsf + 1572864;          // 65536
  float* al2   = wsf + 1638400;
  float* msk   = wsf + 1705984;          // 2560
  float* c1    = wsf + 1709568;          // 262144
  float* c2    = wsf + 1971712;
  float* pene  = wsf + 2233856;          // 524288
  float2* pstats = (float2*)(wsf + 2758144); // 512*250 float2
  u16*  logits = (u16*)(wsf + 3014144);  // 16384000 u16
  u16*  tgtb   = (u16*)(wsf + 11206144);
  u16*  s1b    = (u16*)(wsf + 11337216);
  u16*  s2b    = (u16*)(wsf + 11599360);
  u16*  a1wb   = (u16*)(wsf + 11861504);
  u16*  a2wb   = (u16*)(wsf + 12123648);
  u16*  ofwb   = (u16*)(wsf + 12385792); // 16384000 u16 -> ends ~82 MB
  float* out   = (float*)d_out;

  k_cast_small<<<1152, 256, 0, stream>>>(tgt, s1k, s2k, a1w, a2w, tgtb, s1b, s2b, a1wb, a2wb, msk);
  k_projcast  <<<8128, 256, 0, stream>>>(tgtb, s1b, s2b, a1wb, a2wb, a1b, a2b,
                                         sq1, sk1, sq2, sk2, ofw, ofwb);
  k_bigen     <<<3024, 256, 0, stream>>>(tgtb, ofwb, ofb, logits, pstats,
                                         sq1, sq2, sk1, sk2, v1, v2, pene);
  k_sm        <<<256, 256, 0, stream>>>(pene, v1, v2, s1k, s2k, msk, al1, al2, c1, c2);
  k_out       <<<2048, 256, 0, stream>>>(logits, pstats, al1, al2, c1, c2, tgt, gw, gb, map1, map2, out);
}

// Round 17
// 112.965 us; speedup vs baseline: 1.3801x; 1.0122x over previous
//
#include <hip/hip_runtime.h>

#define NB 8
#define NT 64
#define NS 128
#define TDIM 512
#define NV 32000
#define NEXT 32256
#define NBT 512
#define LNEPS 1e-5f
#define CLG 2.8853900817779268f  // 2*log2(e)

typedef unsigned short u16;
typedef __attribute__((ext_vector_type(8))) short short8;
typedef __attribute__((ext_vector_type(4))) float f32x4;

__device__ __forceinline__ float bf2f(u16 u){ union{unsigned int i; float f;} v; v.i = ((unsigned int)u)<<16; return v.f; }
__device__ __forceinline__ u16 f2bf(float f){ union{float f; unsigned int i;} v; v.f=f; unsigned int r = v.i + 0x7FFFu + ((v.i>>16)&1u); return (u16)(r>>16); }
__device__ __forceinline__ float wsum(float v){
  v += __shfl_xor(v,32); v += __shfl_xor(v,16); v += __shfl_xor(v,8);
  v += __shfl_xor(v,4);  v += __shfl_xor(v,2);  v += __shfl_xor(v,1); return v; }
__device__ __forceinline__ float wmax(float v){
  v = fmaxf(v,__shfl_xor(v,32)); v = fmaxf(v,__shfl_xor(v,16)); v = fmaxf(v,__shfl_xor(v,8));
  v = fmaxf(v,__shfl_xor(v,4));  v = fmaxf(v,__shfl_xor(v,2));  v = fmaxf(v,__shfl_xor(v,1)); return v; }

#define GL2LDS(gp, lp) __builtin_amdgcn_global_load_lds( \
    (__attribute__((address_space(1))) void*)(void*)(gp), \
    (__attribute__((address_space(3))) void*)(void*)(lp), 16, 0, 0)

// ---------------- stage 1: f32->bf16 cast of SMALL operands + fused masks ----------------
__global__ __launch_bounds__(256) void k_cast_small(const float* tgt, const float* s1, const float* s2,
    const float* a1w, const float* a2w,
    u16* tgtb, u16* s1b, u16* s2b, u16* a1wb, u16* a2wb, float* msk)
{
  int blk = blockIdx.x;
  const float* src; u16* dst; int base;
  if(blk < 128){       src=tgt; dst=tgtb;  base=blk; }
  else if(blk < 384){  src=s1;  dst=s1b;   base=blk-128; }
  else if(blk < 640){  src=s2;  dst=s2b;   base=blk-384; }
  else if(blk < 896){  src=a1w; dst=a1wb;  base=blk-640; }
  else {               src=a2w; dst=a2wb;  base=blk-896; }
  size_t off = (size_t)base*2048 + (size_t)threadIdx.x*8;
  float4 x0 = *(const float4*)(src+off);
  float4 x1 = *(const float4*)(src+off+4);
  float xs[8] = {x0.x,x0.y,x0.z,x0.w,x1.x,x1.y,x1.z,x1.w};
  short8 r;
  #pragma unroll
  for(int j=0;j<8;++j) r[j] = (short)f2bf(xs[j]);
  *(short8*)(dst+off) = r;
  if(blk < 640){
    float a = 0.f;
    #pragma unroll
    for(int j=0;j<8;++j) a += fabsf(xs[j]);
    a = wsum(a);
    if((threadIdx.x&63)==0){
      int w = threadIdx.x>>6;
      int midx;
      if(blk<128)      midx = blk*4 + w;
      else if(blk<384) midx = 512 + (blk-128)*4 + w;
      else             midx = 1536 + (blk-384)*4 + w;
      msk[midx] = (a>0.f) ? 1.f : 0.f;
    }
  }
}

// ---------------- MFMA GEMM core (proj path; LDS passed in) ----------------
__device__ __forceinline__ void gemm_core2(u16* Al, u16* Wl, const u16* A, int lda, const u16* W, int ldw,
    float* Cf, int ldc, const float* bias, int K, int bm, int bn, float scale)
{
  const int tid = threadIdx.x, lane = tid&63, wv = tid>>6;
  const int wm = wv>>1, wn = wv&1;
  const int fr = lane&15, fq = lane>>4;
  const int lrow = lane>>2;
  const int lcol = (lane&3)*8;
  f32x4 acc[4][4] = {};
  for(int k0=0;k0<K;k0+=32){
    #pragma unroll
    for(int r=0;r<2;++r){
      int c = wv + 4*r;
      int row = c*16 + lrow;
      const u16* ga = A + (size_t)(bm+row)*lda + k0 + lcol;
      const u16* gw = W + (size_t)(bn+row)*ldw + k0 + lcol;
      GL2LDS(ga, &Al[c*512]);
      GL2LDS(gw, &Wl[c*512]);
    }
    __syncthreads();
    short8 af[4], bfr[4];
    #pragma unroll
    for(int m=0;m<4;++m) af[m] = *(const short8*)&Al[(wm*64 + m*16 + fr)*32 + fq*8];
    #pragma unroll
    for(int n=0;n<4;++n) bfr[n] = *(const short8*)&Wl[(wn*64 + n*16 + fr)*32 + fq*8];
    #pragma unroll
    for(int m=0;m<4;++m)
      #pragma unroll
      for(int n=0;n<4;++n)
        acc[m][n] = __builtin_amdgcn_mfma_f32_16x16x32_bf16(af[m], bfr[n], acc[m][n], 0,0,0);
    __syncthreads();
  }
  #pragma unroll
  for(int m=0;m<4;++m)
    #pragma unroll
    for(int n=0;n<4;++n)
      #pragma unroll
      for(int i=0;i<4;++i){
        int row = bm + wm*64 + m*16 + fq*4 + i;
        int col = bn + wn*64 + n*16 + fr;
        float bv = bias ? bias[col] : 0.f;
        Cf[(size_t)row*ldc + col] = (acc[m][n][i] + bv)*scale;
      }
}

// ---------------- stage 2: proj GEMM (blocks 0..127) + ofw cast (blocks 128..8127) ----------------
__global__ __launch_bounds__(256) void k_projcast(
    const u16* tgtb, const u16* s1, const u16* s2, const u16* w1, const u16* w2,
    const float* b1, const float* b2,
    float* sq1, float* sk1, float* sq2, float* sk2,
    const float* ofw, u16* ofwb)
{
  __shared__ u16 Al[128*32];
  __shared__ u16 Wl[128*32];
  if(blockIdx.x < 128){
    int p = blockIdx.x;
    int z = p>>5, y = (p>>2)&7, x = p&3;
    int Mt = (z&1) ? 1024 : 512;
    int bm = y*128; if(bm >= Mt) return;
    const u16* Ap = (z&1) ? ((z>>1) ? s2 : s1) : tgtb;
    const u16* Wp = ((z>>1) ? w2 : w1) + ((z&1) ? TDIM : 0);
    float* Cf = (z==0) ? sq1 : (z==1) ? sk1 : (z==2) ? sq2 : sk2;
    const float* bp = (z&1) ? nullptr : ((z>>1) ? b2 : b1);
    gemm_core2(Al, Wl, Ap, TDIM, Wp, 2*TDIM, Cf, TDIM, bp, TDIM, bm, x*128, CLG);
    return;
  }
  size_t off = (size_t)(blockIdx.x-128)*2048 + (size_t)threadIdx.x*8;
  float4 x0 = *(const float4*)(ofw+off);
  float4 x1 = *(const float4*)(ofw+off+4);
  float xs[8] = {x0.x,x0.y,x0.z,x0.w,x1.x,x1.y,x1.z,x1.w};
  short8 r;
  #pragma unroll
  for(int j=0;j<8;++j) r[j] = (short)f2bf(xs[j]);
  *(short8*)(ofwb+off) = r;
}

// ---------------- stage 3: big GEMM (0..1999; 64x128, dbuf + counted vmcnt) + energy (2000..3023) ----------------
__global__ __launch_bounds__(256) void k_bigen(const u16* A, const u16* W, const float* bias,
    u16* logits, float2* pstats,
    const float* sq1, const float* sq2, const float* sk1, const float* sk2,
    const float* v1p, const float* v2p, float* pene)
{
  union __align__(16) SMem {
    struct { u16 At[2][64*32]; u16 Wt[2][128*32]; float ps[2][64]; float pq[2][64]; } big;
    float sk[32*65];
  };
  __shared__ SMem smem;
  const int tid = threadIdx.x, lane = tid&63, wv = tid>>6;

  if(blockIdx.x < 2000){
    int lid = (blockIdx.x&7)*250 + (blockIdx.x>>3);   // bijective (2000%8==0)
    int bm = (lid&7)*64, bn = (lid>>3)*128, nb = lid>>3;
    const int wm = wv>>1, wn = wv&1;
    const int fr = lane&15, fq = lane>>4;
    const int lrow = lane>>2;
    const int lcol = (lane&3)*8;
    f32x4 acc[2][4] = {};

    #define STAGE_BIG(SL, K0) { \
      GL2LDS(A + (size_t)(bm + wv*16 + lrow)*512 + (K0) + lcol, &smem.big.At[SL][wv*512]); \
      GL2LDS(W + (size_t)(bn + wv*16 + lrow)*512 + (K0) + lcol, &smem.big.Wt[SL][wv*512]); \
      GL2LDS(W + (size_t)(bn + (wv+4)*16 + lrow)*512 + (K0) + lcol, &smem.big.Wt[SL][(wv+4)*512]); }

    STAGE_BIG(0, 0);
    STAGE_BIG(1, 32);
    #pragma unroll
    for(int kk=0; kk<16; ++kk){
      const int sl = kk&1;                  // compile-time after full unroll
      if(kk < 15) { asm volatile("s_waitcnt vmcnt(3)" ::: "memory"); }   // my slot-sl loads done; next slot in flight
      else        { asm volatile("s_waitcnt vmcnt(0)" ::: "memory"); }
      asm volatile("s_barrier" ::: "memory");
      short8 af[2], bfr[4];
      #pragma unroll
      for(int m=0;m<2;++m) af[m] = *(const short8*)&smem.big.At[sl][(wm*32 + m*16 + fr)*32 + fq*8];
      #pragma unroll
      for(int n=0;n<4;++n) bfr[n] = *(const short8*)&smem.big.Wt[sl][(wn*64 + n*16 + fr)*32 + fq*8];
      #pragma unroll
      for(int m=0;m<2;++m)
        #pragma unroll
        for(int n=0;n<4;++n)
          acc[m][n] = __builtin_amdgcn_mfma_f32_16x16x32_bf16(af[m], bfr[n], acc[m][n], 0,0,0);
      asm volatile("s_waitcnt lgkmcnt(0)" ::: "memory");   // my ds_reads drained before slot reuse
      asm volatile("s_barrier" ::: "memory");
      if(kk+2 < 16) STAGE_BIG(sl, (kk+2)*32);
    }
    #undef STAGE_BIG

    #pragma unroll
    for(int m=0;m<2;++m){
      float rs_[4]={0,0,0,0}, rq_[4]={0,0,0,0};
      #pragma unroll
      for(int n=0;n<4;++n)
        #pragma unroll
        for(int i=0;i<4;++i){
          int row = bm + wm*32 + m*16 + fq*4 + i;
          int col = bn + wn*64 + n*16 + fr;
          float v = acc[m][n][i] + bias[col];
          logits[(size_t)row*NV + col] = f2bf(v);
          rs_[i] += v; rq_[i] += v*v;
        }
      #pragma unroll
      for(int i=0;i<4;++i){
        float a=rs_[i], q=rq_[i];
        a+=__shfl_xor(a,1); a+=__shfl_xor(a,2); a+=__shfl_xor(a,4); a+=__shfl_xor(a,8);
        q+=__shfl_xor(q,1); q+=__shfl_xor(q,2); q+=__shfl_xor(q,4); q+=__shfl_xor(q,8);
        if(fr==0){ int lr = wm*32 + m*16 + fq*4 + i; smem.big.ps[wn][lr]=a; smem.big.pq[wn][lr]=q; }
      }
    }
    __syncthreads();
    if(tid<64){
      float2 pv;
      pv.x = smem.big.ps[0][tid]+smem.big.ps[1][tid];
      pv.y = smem.big.pq[0][tid]+smem.big.pq[1][tid];
      pstats[(size_t)(bm+tid)*250 + nb] = pv;
    }
    return;
  }

  // energy path
  int id = blockIdx.x - 2000;
  int lid = (id&7)*128 + (id>>3);  // bijective, 1024%8==0
  int src = lid>>9, b = (lid>>6)&7, tc = (lid>>4)&3, sc = (lid>>2)&3, eq = lid&3;
  const float* SQ = src? sq2:sq1;
  const float* SK = src? sk2:sk1;
  const float* vp = src? v2p:v1p;
  int t0 = tc*16, s0 = sc*32;
  int strow = tid&31, trow = tid>>5;

  float acc_a = 0.f, acc_b = 0.f;
  const float* sqa = SQ + (size_t)(b*64 + t0 + trow)*512;
  const float* sqb = sqa + 8*512;

  for(int ec=eq*2; ec<eq*2+2; ++ec){
    {
      int r = tid>>3, c0 = (tid&7)*8;
      const float* sp = SK + (size_t)(b*128 + s0 + r)*512 + ec*64 + c0;
      float4 A0 = *(const float4*)sp;
      float4 A1 = *(const float4*)(sp+4);
      float* dp = &smem.sk[r*65 + c0];
      dp[0]=A0.x; dp[1]=A0.y; dp[2]=A0.z; dp[3]=A0.w;
      dp[4]=A1.x; dp[5]=A1.y; dp[6]=A1.z; dp[7]=A1.w;
    }
    __syncthreads();
    #pragma unroll
    for(int sub=0; sub<4; ++sub){
      int e0 = ec*64 + sub*16;
      float4 V0 = *(const float4*)(vp+e0),    V1 = *(const float4*)(vp+e0+4);
      float4 V2 = *(const float4*)(vp+e0+8),  V3 = *(const float4*)(vp+e0+12);
      float4 QA0 = *(const float4*)(sqa+e0),  QA1 = *(const float4*)(sqa+e0+4);
      float4 QA2 = *(const float4*)(sqa+e0+8),QA3 = *(const float4*)(sqa+e0+12);
      float4 QB0 = *(const float4*)(sqb+e0),  QB1 = *(const float4*)(sqb+e0+4);
      float4 QB2 = *(const float4*)(sqb+e0+8),QB3 = *(const float4*)(sqb+e0+12);
      float vv[16] = {V0.x,V0.y,V0.z,V0.w,V1.x,V1.y,V1.z,V1.w,V2.x,V2.y,V2.z,V2.w,V3.x,V3.y,V3.z,V3.w};
      float qa[16] = {QA0.x,QA0.y,QA0.z,QA0.w,QA1.x,QA1.y,QA1.z,QA1.w,QA2.x,QA2.y,QA2.z,QA2.w,QA3.x,QA3.y,QA3.z,QA3.w};
      float qb[16] = {QB0.x,QB0.y,QB0.z,QB0.w,QB1.x,QB1.y,QB1.z,QB1.w,QB2.x,QB2.y,QB2.z,QB2.w,QB3.x,QB3.y,QB3.z,QB3.w};
      const float* skr = &smem.sk[strow*65 + sub*16];
      #pragma unroll
      for(int e=0;e<16;++e){
        float skv = skr[e];
        float ya = qa[e] + skv;
        float yb = qb[e] + skv;
        float ra = __builtin_amdgcn_rcpf(__builtin_amdgcn_exp2f(ya) + 1.f);
        float rb = __builtin_amdgcn_rcpf(__builtin_amdgcn_exp2f(yb) + 1.f);
        acc_a = __builtin_fmaf(vv[e], ra, acc_a);
        acc_b = __builtin_fmaf(vv[e], rb, acc_b);
      }
    }
    __syncthreads();
  }
  size_t ia = (size_t)((eq*2+src)*512 + b*64 + t0 + trow)*128 + s0 + strow;
  pene[ia] = acc_a;
  pene[ia + 8*128] = acc_b;
}

// ---------------- softmax + att-LN + weighted sum, block per (src,b,4t) ----------------
__global__ __launch_bounds__(256) void k_sm(
  const float* pene, const float* v1p, const float* v2p,
  const float* k1g, const float* k2g, const float* msk,
  float* al1, float* al2, float* c1, float* c2)
{
  int lid = (blockIdx.x&7)*32 + (blockIdx.x>>3);  // bijective, 256%8==0
  int src = lid>>7, b = (lid>>4)&7, tq = lid&15;
  int tid = threadIdx.x, lane = tid&63, wv = tid>>6;
  int t = tq*4 + wv, bt = b*64 + t;
  const float* vp = src? v2p:v1p;
  const float* kg = src? k2g:k1g;
  float* al = src? al2:al1;
  float* cc = src? c2:c1;
  const float* km_g = msk + 512 + src*1024 + b*128;
  __shared__ float aw_lds[4][132];
  __shared__ float qm_lds[4];

  {
    float vsp = 0.f;
    #pragma unroll
    for(int r2=0;r2<8;++r2) vsp += vp[lane + 64*r2];
    float Vsum = wsum(vsp);
    float qm = msk[bt];
    float km0 = km_g[lane], km1 = km_g[lane+64];
    size_t pbase = (size_t)(src*512 + bt)*128;
    float p0a = pene[pbase + lane]          + pene[pbase + 131072 + lane];
    float p0b = pene[pbase + 262144 + lane] + pene[pbase + 393216 + lane];
    float p1a = pene[pbase + lane + 64]          + pene[pbase + 131072 + lane + 64];
    float p1b = pene[pbase + 262144 + lane + 64] + pene[pbase + 393216 + lane + 64];
    float s0v = Vsum - 2.f*(p0a + p0b);
    float s1v = Vsum - 2.f*(p1a + p1b);
    float a0 = s0v*km0*qm, a1 = s1v*km1*qm;
    float sm = wsum(a0+a1), sqq = wsum(a0*a0+a1*a1);
    float m0 = km0!=0.f ? s0v : -1e30f;
    float m1 = km1!=0.f ? s1v : -1e30f;
    float mx = wmax(fmaxf(m0,m1));
    float e0 = km0!=0.f ? __expf(s0v-mx) : 0.f;
    float e1 = km1!=0.f ? __expf(s1v-mx) : 0.f;
    float den = wsum(e0+e1);
    float mean = sm/128.f;
    float inv  = rsqrtf(sqq/128.f - mean*mean + LNEPS);
    al[(size_t)bt*128 + lane]      = (a0-mean)*inv;
    al[(size_t)bt*128 + lane + 64] = (a1-mean)*inv;
    float rden = 1.f/den;
    aw_lds[wv][lane]      = e0*rden;
    aw_lds[wv][lane+64]   = e1*rden;
    if(lane==0) qm_lds[wv] = qm;
  }
  __syncthreads();
  {
    float acc[4][2] = {};
    const float* kb = kg + (size_t)b*128*512;
    for(int s=0;s<128;++s){
      float kv0 = kb[(size_t)s*512 + tid];
      float kv1 = kb[(size_t)s*512 + tid + 256];
      #pragma unroll
      for(int w=0;w<4;++w){
        float a = aw_lds[w][s];
        acc[w][0] = __builtin_fmaf(a, kv0, acc[w][0]);
        acc[w][1] = __builtin_fmaf(a, kv1, acc[w][1]);
      }
    }
    #pragma unroll
    for(int w=0;w<4;++w){
      float qm = qm_lds[w];
      size_t o = (size_t)(b*64 + tq*4 + w)*512;
      cc[o + tid]       = qm*acc[w][0];
      cc[o + tid + 256] = qm*acc[w][1];
    }
  }
}

// ---------------- out: gate + stats-reduce + LN*p0 + pad + hash-patched store ----------------
__global__ __launch_bounds__(256) void k_out(const u16* logits, const float2* pstats,
    const float* al1, const float* al2, const float* c1, const float* c2,
    const float* tgt, const float* gw, const float* gb,
    const int* map1, const int* map2, float* out)
{
  int row = blockIdx.x>>2, q = blockIdx.x&3, b = row>>6;
  int tid = threadIdx.x, lane = tid&63, wv = tid>>6;
  __shared__ float gred[4][3], rs[4], rq[4], st[2], pl_s[3];
  __shared__ int hkey[1024];
  __shared__ float hval[1024];
  __shared__ unsigned int bmap[252];

  #pragma unroll
  for(int r=0;r<4;++r){ hkey[tid+256*r] = -1; hval[tid+256*r] = 0.f; }
  if(tid < 252) bmap[tid] = 0u;

  {
    float t0v = tgt[(size_t)row*512+tid], t1v = tgt[(size_t)row*512+tid+256];
    float c10 = c1[(size_t)row*512+tid],  c11 = c1[(size_t)row*512+tid+256];
    float c20 = c2[(size_t)row*512+tid],  c21 = c2[(size_t)row*512+tid+256];
    #pragma unroll
    for(int p=0;p<3;++p){
      const float* gp = gw + p*1536;
      float a = gp[tid]*t0v + gp[tid+256]*t1v
              + gp[512+tid]*c10 + gp[768+tid]*c11
              + gp[1024+tid]*c20 + gp[1280+tid]*c21;
      a = wsum(a);
      if(lane==0) gred[wv][p] = a;
    }
  }
  {
    float s=0.f, qv=0.f;
    if(tid < 250){ float2 pv = pstats[(size_t)row*250 + tid]; s = pv.x; qv = pv.y; }
    s = wsum(s); qv = wsum(qv);
    if(lane==0){ rs[wv]=s; rq[wv]=qv; }
  }
  __syncthreads();
  if(tid==0){
    float S = rs[0]+rs[1]+rs[2]+rs[3];
    float Q = rq[0]+rq[1]+rq[2]+rq[3];
    float mean = S/(float)NV;
    float var  = Q/(float)NV - mean*mean;
    st[0] = mean; st[1] = rsqrtf(var+LNEPS);
    float g0 = gred[0][0]+gred[1][0]+gred[2][0]+gred[3][0] + gb[0];
    float g1 = gred[0][1]+gred[1][1]+gred[2][1]+gred[3][1] + gb[1];
    float g2 = gred[0][2]+gred[1][2]+gred[2][2]+gred[3][2] + gb[2];
    float m = fmaxf(g0, fmaxf(g1, g2));
    float e0=__expf(g0-m), e1=__expf(g1-m), e2=__expf(g2-m);
    float sI = 1.f/(e0+e1+e2);
    pl_s[0]=e0*sI; pl_s[1]=e1*sI; pl_s[2]=e2*sI;
  }
  __syncthreads();

  int elo = q*8064;
  {
    int src = tid>>7, sl = tid&127;
    int e = (src ? map2 : map1)[b*128 + sl];
    if(e >= elo && e < elo+8064){
      float val = pl_s[1+src] * (src ? al2 : al1)[(size_t)row*128 + sl];
      unsigned int h = ((unsigned int)e * 2654435761u) >> 22;
      for(;;){
        int old = atomicCAS(&hkey[h], -1, e);
        if(old == -1 || old == e){ atomicAdd(&hval[h], val); break; }
        h = (h+1) & 1023;
      }
      int rel = e - elo;
      atomicOr(&bmap[rel>>5], 1u << (rel&31));
    }
  }
  __syncthreads();

  float mean = st[0], inv = st[1], p0 = pl_s[0];
  const u16* Lr = logits + (size_t)row*NV;
  float* orow = out + (size_t)row*NEXT;
  for(int i=q*2016+tid; i<(q+1)*2016; i+=256){
    int e0 = i*4;
    float4 r;
    if(e0 < NV){
      const u16* L = &Lr[e0];
      r.x = p0*(bf2f(L[0])-mean)*inv;
      r.y = p0*(bf2f(L[1])-mean)*inv;
      r.z = p0*(bf2f(L[2])-mean)*inv;
      r.w = p0*(bf2f(L[3])-mean)*inv;
    } else { r.x=r.y=r.z=r.w=0.f; }
    int rel = e0 - elo;
    unsigned int w4 = (bmap[rel>>5] >> (rel&31)) & 0xFu;
    if(w4){
      #pragma unroll
      for(int j=0;j<4;++j){
        if(w4 & (1u<<j)){
          int e = e0 + j;
          unsigned int h = ((unsigned int)e * 2654435761u) >> 22;
          while(hkey[h] != e) h = (h+1) & 1023;
          float pv = hval[h];
          if(j==0) r.x += pv; else if(j==1) r.y += pv; else if(j==2) r.z += pv; else r.w += pv;
        }
      }
    }
    *(float4*)&orow[e0] = r;
  }
}

extern "C" void kernel_launch(void* const* d_in, const int* in_sizes, int n_in,
                              void* d_out, int out_size, void* d_ws, size_t ws_size,
                              hipStream_t stream)
{
  const float* tgt  = (const float*)d_in[0];
  const float* s1k  = (const float*)d_in[1];
  const float* s2k  = (const float*)d_in[2];
  const int*   map1 = (const int*)d_in[3];
  const int*   map2 = (const int*)d_in[4];
  const float* ofw  = (const float*)d_in[5];
  const float* ofb  = (const float*)d_in[6];
  const float* a1w  = (const float*)d_in[7];
  const float* a1b  = (const float*)d_in[8];
  const float* v1   = (const float*)d_in[9];
  const float* a2w  = (const float*)d_in[10];
  const float* a2b  = (const float*)d_in[11];
  const float* v2   = (const float*)d_in[12];
  const float* gw   = (const float*)d_in[13];
  const float* gb   = (const float*)d_in[14];

  float* wsf   = (float*)d_ws;
  float* sq1   = wsf;                    // 262144
  float* sq2   = wsf + 262144;
  float* sk1   = wsf + 524288;           // 524288
  float* sk2   = wsf + 1048576;
  float* al1   = wsf + 1572864;          // 65536
  float* al2   = wsf + 1638400;
  float* msk   = wsf + 1705984;          // 2560
  float* c1    = wsf + 1709568;          // 262144
  float* c2    = wsf + 1971712;
  float* pene  = wsf + 2233856;          // 524288
  float2* pstats = (float2*)(wsf + 2758144); // 512*250 float2
  u16*  logits = (u16*)(wsf + 3014144);  // 16384000 u16
  u16*  tgtb   = (u16*)(wsf + 11206144);
  u16*  s1b    = (u16*)(wsf + 11337216);
  u16*  s2b    = (u16*)(wsf + 11599360);
  u16*  a1wb   = (u16*)(wsf + 11861504);
  u16*  a2wb   = (u16*)(wsf + 12123648);
  u16*  ofwb   = (u16*)(wsf + 12385792); // 16384000 u16 -> ends ~82 MB
  float* out   = (float*)d_out;

  k_cast_small<<<1152, 256, 0, stream>>>(tgt, s1k, s2k, a1w, a2w, tgtb, s1b, s2b, a1wb, a2wb, msk);
  k_projcast  <<<8128, 256, 0, stream>>>(tgtb, s1b, s2b, a1wb, a2wb, a1b, a2b,
                                         sq1, sk1, sq2, sk2, ofw, ofwb);
  k_bigen     <<<3024, 256, 0, stream>>>(tgtb, ofwb, ofb, logits, pstats,
                                         sq1, sq2, sk1, sk2, v1, v2, pene);
  k_sm        <<<256, 256, 0, stream>>>(pene, v1, v2, s1k, s2k, msk, al1, al2, c1, c2);
  k_out       <<<2048, 256, 0, stream>>>(logits, pstats, al1, al2, c1, c2, tgt, gw, gb, map1, map2, out);
}

// Round 18
// 112.222 us; speedup vs baseline: 1.3892x; 1.0066x over previous
//
#include <hip/hip_runtime.h>

#define NB 8
#define NT 64
#define NS 128
#define TDIM 512
#define NV 32000
#define NEXT 32256
#define NBT 512
#define LNEPS 1e-5f
#define CLG 2.8853900817779268f  // 2*log2(e)

typedef unsigned short u16;
typedef __attribute__((ext_vector_type(8))) short short8;
typedef __attribute__((ext_vector_type(4))) float f32x4;

__device__ __forceinline__ float bf2f(u16 u){ union{unsigned int i; float f;} v; v.i = ((unsigned int)u)<<16; return v.f; }
__device__ __forceinline__ u16 f2bf(float f){ union{float f; unsigned int i;} v; v.f=f; unsigned int r = v.i + 0x7FFFu + ((v.i>>16)&1u); return (u16)(r>>16); }
__device__ __forceinline__ float wsum(float v){
  v += __shfl_xor(v,32); v += __shfl_xor(v,16); v += __shfl_xor(v,8);
  v += __shfl_xor(v,4);  v += __shfl_xor(v,2);  v += __shfl_xor(v,1); return v; }
__device__ __forceinline__ float wmax(float v){
  v = fmaxf(v,__shfl_xor(v,32)); v = fmaxf(v,__shfl_xor(v,16)); v = fmaxf(v,__shfl_xor(v,8));
  v = fmaxf(v,__shfl_xor(v,4));  v = fmaxf(v,__shfl_xor(v,2));  v = fmaxf(v,__shfl_xor(v,1)); return v; }

#define GL2LDS(gp, lp) __builtin_amdgcn_global_load_lds( \
    (__attribute__((address_space(1))) void*)(void*)(gp), \
    (__attribute__((address_space(3))) void*)(void*)(lp), 16, 0, 0)

// ---------------- stage 1: f32->bf16 cast of SMALL operands + fused masks ----------------
__global__ __launch_bounds__(256) void k_cast_small(const float* tgt, const float* s1, const float* s2,
    const float* a1w, const float* a2w,
    u16* tgtb, u16* s1b, u16* s2b, u16* a1wb, u16* a2wb, float* msk)
{
  int blk = blockIdx.x;
  const float* src; u16* dst; int base;
  if(blk < 128){       src=tgt; dst=tgtb;  base=blk; }
  else if(blk < 384){  src=s1;  dst=s1b;   base=blk-128; }
  else if(blk < 640){  src=s2;  dst=s2b;   base=blk-384; }
  else if(blk < 896){  src=a1w; dst=a1wb;  base=blk-640; }
  else {               src=a2w; dst=a2wb;  base=blk-896; }
  size_t off = (size_t)base*2048 + (size_t)threadIdx.x*8;
  float4 x0 = *(const float4*)(src+off);
  float4 x1 = *(const float4*)(src+off+4);
  float xs[8] = {x0.x,x0.y,x0.z,x0.w,x1.x,x1.y,x1.z,x1.w};
  short8 r;
  #pragma unroll
  for(int j=0;j<8;++j) r[j] = (short)f2bf(xs[j]);
  *(short8*)(dst+off) = r;
  if(blk < 640){
    float a = 0.f;
    #pragma unroll
    for(int j=0;j<8;++j) a += fabsf(xs[j]);
    a = wsum(a);
    if((threadIdx.x&63)==0){
      int w = threadIdx.x>>6;
      int midx;
      if(blk<128)      midx = blk*4 + w;
      else if(blk<384) midx = 512 + (blk-128)*4 + w;
      else             midx = 1536 + (blk-384)*4 + w;
      msk[midx] = (a>0.f) ? 1.f : 0.f;
    }
  }
}

// ---------------- MFMA GEMM core (proj path; LDS passed in) ----------------
__device__ __forceinline__ void gemm_core2(u16* Al, u16* Wl, const u16* A, int lda, const u16* W, int ldw,
    float* Cf, int ldc, const float* bias, int K, int bm, int bn, float scale)
{
  const int tid = threadIdx.x, lane = tid&63, wv = tid>>6;
  const int wm = wv>>1, wn = wv&1;
  const int fr = lane&15, fq = lane>>4;
  const int lrow = lane>>2;
  const int lcol = (lane&3)*8;
  f32x4 acc[4][4] = {};
  for(int k0=0;k0<K;k0+=32){
    #pragma unroll
    for(int r=0;r<2;++r){
      int c = wv + 4*r;
      int row = c*16 + lrow;
      const u16* ga = A + (size_t)(bm+row)*lda + k0 + lcol;
      const u16* gw = W + (size_t)(bn+row)*ldw + k0 + lcol;
      GL2LDS(ga, &Al[c*512]);
      GL2LDS(gw, &Wl[c*512]);
    }
    __syncthreads();
    short8 af[4], bfr[4];
    #pragma unroll
    for(int m=0;m<4;++m) af[m] = *(const short8*)&Al[(wm*64 + m*16 + fr)*32 + fq*8];
    #pragma unroll
    for(int n=0;n<4;++n) bfr[n] = *(const short8*)&Wl[(wn*64 + n*16 + fr)*32 + fq*8];
    #pragma unroll
    for(int m=0;m<4;++m)
      #pragma unroll
      for(int n=0;n<4;++n)
        acc[m][n] = __builtin_amdgcn_mfma_f32_16x16x32_bf16(af[m], bfr[n], acc[m][n], 0,0,0);
    __syncthreads();
  }
  #pragma unroll
  for(int m=0;m<4;++m)
    #pragma unroll
    for(int n=0;n<4;++n)
      #pragma unroll
      for(int i=0;i<4;++i){
        int row = bm + wm*64 + m*16 + fq*4 + i;
        int col = bn + wn*64 + n*16 + fr;
        float bv = bias ? bias[col] : 0.f;
        Cf[(size_t)row*ldc + col] = (acc[m][n][i] + bv)*scale;
      }
}

// ---------------- stage 2: proj GEMM (blocks 0..127) + ofw cast (blocks 128..8127) ----------------
__global__ __launch_bounds__(256) void k_projcast(
    const u16* tgtb, const u16* s1, const u16* s2, const u16* w1, const u16* w2,
    const float* b1, const float* b2,
    float* sq1, float* sk1, float* sq2, float* sk2,
    const float* ofw, u16* ofwb)
{
  __shared__ u16 Al[128*32];
  __shared__ u16 Wl[128*32];
  if(blockIdx.x < 128){
    int p = blockIdx.x;
    int z = p>>5, y = (p>>2)&7, x = p&3;
    int Mt = (z&1) ? 1024 : 512;
    int bm = y*128; if(bm >= Mt) return;
    const u16* Ap = (z&1) ? ((z>>1) ? s2 : s1) : tgtb;
    const u16* Wp = ((z>>1) ? w2 : w1) + ((z&1) ? TDIM : 0);
    float* Cf = (z==0) ? sq1 : (z==1) ? sk1 : (z==2) ? sq2 : sk2;
    const float* bp = (z&1) ? nullptr : ((z>>1) ? b2 : b1);
    gemm_core2(Al, Wl, Ap, TDIM, Wp, 2*TDIM, Cf, TDIM, bp, TDIM, bm, x*128, CLG);
    return;
  }
  size_t off = (size_t)(blockIdx.x-128)*2048 + (size_t)threadIdx.x*8;
  float4 x0 = *(const float4*)(ofw+off);
  float4 x1 = *(const float4*)(ofw+off+4);
  float xs[8] = {x0.x,x0.y,x0.z,x0.w,x1.x,x1.y,x1.z,x1.w};
  short8 r;
  #pragma unroll
  for(int j=0;j<8;++j) r[j] = (short)f2bf(xs[j]);
  *(short8*)(ofwb+off) = r;
}

// ---------------- stage 3: big GEMM (0..1999; 64x128, dbuf + counted vmcnt + LDS swizzle) + energy ----------------
__global__ __launch_bounds__(256) void k_bigen(const u16* A, const u16* W, const float* bias,
    u16* logits, float2* pstats,
    const float* sq1, const float* sq2, const float* sk1, const float* sk2,
    const float* v1p, const float* v2p, float* pene)
{
  union __align__(16) SMem {
    struct { u16 At[2][64*32]; u16 Wt[2][128*32]; float ps[2][64]; float pq[2][64]; } big;
    float sk[32*65];
  };
  __shared__ SMem smem;
  const int tid = threadIdx.x, lane = tid&63, wv = tid>>6;

  if(blockIdx.x < 2000){
    int lid = (blockIdx.x&7)*250 + (blockIdx.x>>3);   // bijective (2000%8==0)
    int bm = (lid&7)*64, bn = (lid>>3)*128, nb = lid>>3;
    const int wm = wv>>1, wn = wv&1;
    const int fr = lane&15, fq = lane>>4;
    const int lrow = lane>>2;
    // pre-swizzled global source chunk: LDS[row][chunk] holds global[row][chunk ^ ((row>>1)&3)]
    const int lcolS = (((lane&3) ^ ((lrow>>1)&3)))*8;
    const int fqS  = (fq ^ ((fr>>1)&3))*8;           // read-side inverse of the same involution
    f32x4 acc[2][4] = {};

    #define STAGE_BIG(SL, K0) { \
      GL2LDS(A + (size_t)(bm + wv*16 + lrow)*512 + (K0) + lcolS, &smem.big.At[SL][wv*512]); \
      GL2LDS(W + (size_t)(bn + wv*16 + lrow)*512 + (K0) + lcolS, &smem.big.Wt[SL][wv*512]); \
      GL2LDS(W + (size_t)(bn + (wv+4)*16 + lrow)*512 + (K0) + lcolS, &smem.big.Wt[SL][(wv+4)*512]); }

    STAGE_BIG(0, 0);
    STAGE_BIG(1, 32);
    #pragma unroll
    for(int kk=0; kk<16; ++kk){
      const int sl = kk&1;                  // compile-time after full unroll
      if(kk < 15) { asm volatile("s_waitcnt vmcnt(3)" ::: "memory"); }
      else        { asm volatile("s_waitcnt vmcnt(0)" ::: "memory"); }
      asm volatile("s_barrier" ::: "memory");
      short8 af[2], bfr[4];
      #pragma unroll
      for(int m=0;m<2;++m) af[m] = *(const short8*)&smem.big.At[sl][(wm*32 + m*16 + fr)*32 + fqS];
      #pragma unroll
      for(int n=0;n<4;++n) bfr[n] = *(const short8*)&smem.big.Wt[sl][(wn*64 + n*16 + fr)*32 + fqS];
      #pragma unroll
      for(int m=0;m<2;++m)
        #pragma unroll
        for(int n=0;n<4;++n)
          acc[m][n] = __builtin_amdgcn_mfma_f32_16x16x32_bf16(af[m], bfr[n], acc[m][n], 0,0,0);
      asm volatile("s_waitcnt lgkmcnt(0)" ::: "memory");
      asm volatile("s_barrier" ::: "memory");
      if(kk+2 < 16) STAGE_BIG(sl, (kk+2)*32);
    }
    #undef STAGE_BIG

    #pragma unroll
    for(int m=0;m<2;++m){
      float rs_[4]={0,0,0,0}, rq_[4]={0,0,0,0};
      #pragma unroll
      for(int n=0;n<4;++n)
        #pragma unroll
        for(int i=0;i<4;++i){
          int row = bm + wm*32 + m*16 + fq*4 + i;
          int col = bn + wn*64 + n*16 + fr;
          float v = acc[m][n][i] + bias[col];
          logits[(size_t)row*NV + col] = f2bf(v);
          rs_[i] += v; rq_[i] += v*v;
        }
      #pragma unroll
      for(int i=0;i<4;++i){
        float a=rs_[i], q=rq_[i];
        a+=__shfl_xor(a,1); a+=__shfl_xor(a,2); a+=__shfl_xor(a,4); a+=__shfl_xor(a,8);
        q+=__shfl_xor(q,1); q+=__shfl_xor(q,2); q+=__shfl_xor(q,4); q+=__shfl_xor(q,8);
        if(fr==0){ int lr = wm*32 + m*16 + fq*4 + i; smem.big.ps[wn][lr]=a; smem.big.pq[wn][lr]=q; }
      }
    }
    __syncthreads();
    if(tid<64){
      float2 pv;
      pv.x = smem.big.ps[0][tid]+smem.big.ps[1][tid];
      pv.y = smem.big.pq[0][tid]+smem.big.pq[1][tid];
      pstats[(size_t)(bm+tid)*250 + nb] = pv;
    }
    return;
  }

  // energy path
  int id = blockIdx.x - 2000;
  int lid = (id&7)*128 + (id>>3);  // bijective, 1024%8==0
  int src = lid>>9, b = (lid>>6)&7, tc = (lid>>4)&3, sc = (lid>>2)&3, eq = lid&3;
  const float* SQ = src? sq2:sq1;
  const float* SK = src? sk2:sk1;
  const float* vp = src? v2p:v1p;
  int t0 = tc*16, s0 = sc*32;
  int strow = tid&31, trow = tid>>5;

  float acc_a = 0.f, acc_b = 0.f;
  const float* sqa = SQ + (size_t)(b*64 + t0 + trow)*512;
  const float* sqb = sqa + 8*512;

  for(int ec=eq*2; ec<eq*2+2; ++ec){
    {
      int r = tid>>3, c0 = (tid&7)*8;
      const float* sp = SK + (size_t)(b*128 + s0 + r)*512 + ec*64 + c0;
      float4 A0 = *(const float4*)sp;
      float4 A1 = *(const float4*)(sp+4);
      float* dp = &smem.sk[r*65 + c0];
      dp[0]=A0.x; dp[1]=A0.y; dp[2]=A0.z; dp[3]=A0.w;
      dp[4]=A1.x; dp[5]=A1.y; dp[6]=A1.z; dp[7]=A1.w;
    }
    __syncthreads();
    #pragma unroll
    for(int sub=0; sub<4; ++sub){
      int e0 = ec*64 + sub*16;
      float4 V0 = *(const float4*)(vp+e0),    V1 = *(const float4*)(vp+e0+4);
      float4 V2 = *(const float4*)(vp+e0+8),  V3 = *(const float4*)(vp+e0+12);
      float4 QA0 = *(const float4*)(sqa+e0),  QA1 = *(const float4*)(sqa+e0+4);
      float4 QA2 = *(const float4*)(sqa+e0+8),QA3 = *(const float4*)(sqa+e0+12);
      float4 QB0 = *(const float4*)(sqb+e0),  QB1 = *(const float4*)(sqb+e0+4);
      float4 QB2 = *(const float4*)(sqb+e0+8),QB3 = *(const float4*)(sqb+e0+12);
      float vv[16] = {V0.x,V0.y,V0.z,V0.w,V1.x,V1.y,V1.z,V1.w,V2.x,V2.y,V2.z,V2.w,V3.x,V3.y,V3.z,V3.w};
      float qa[16] = {QA0.x,QA0.y,QA0.z,QA0.w,QA1.x,QA1.y,QA1.z,QA1.w,QA2.x,QA2.y,QA2.z,QA2.w,QA3.x,QA3.y,QA3.z,QA3.w};
      float qb[16] = {QB0.x,QB0.y,QB0.z,QB0.w,QB1.x,QB1.y,QB1.z,QB1.w,QB2.x,QB2.y,QB2.z,QB2.w,QB3.x,QB3.y,QB3.z,QB3.w};
      const float* skr = &smem.sk[strow*65 + sub*16];
      #pragma unroll
      for(int e=0;e<16;++e){
        float skv = skr[e];
        float ya = qa[e] + skv;
        float yb = qb[e] + skv;
        float ra = __builtin_amdgcn_rcpf(__builtin_amdgcn_exp2f(ya) + 1.f);
        float rb = __builtin_amdgcn_rcpf(__builtin_amdgcn_exp2f(yb) + 1.f);
        acc_a = __builtin_fmaf(vv[e], ra, acc_a);
        acc_b = __builtin_fmaf(vv[e], rb, acc_b);
      }
    }
    __syncthreads();
  }
  size_t ia = (size_t)((eq*2+src)*512 + b*64 + t0 + trow)*128 + s0 + strow;
  pene[ia] = acc_a;
  pene[ia + 8*128] = acc_b;
}

// ---------------- softmax + att-LN + weighted sum, block per (src,b,4t) ----------------
__global__ __launch_bounds__(256) void k_sm(
  const float* pene, const float* v1p, const float* v2p,
  const float* k1g, const float* k2g, const float* msk,
  float* al1, float* al2, float* c1, float* c2)
{
  int lid = (blockIdx.x&7)*32 + (blockIdx.x>>3);  // bijective, 256%8==0
  int src = lid>>7, b = (lid>>4)&7, tq = lid&15;
  int tid = threadIdx.x, lane = tid&63, wv = tid>>6;
  int t = tq*4 + wv, bt = b*64 + t;
  const float* vp = src? v2p:v1p;
  const float* kg = src? k2g:k1g;
  float* al = src? al2:al1;
  float* cc = src? c2:c1;
  const float* km_g = msk + 512 + src*1024 + b*128;
  __shared__ float aw_lds[4][132];
  __shared__ float qm_lds[4];

  {
    float vsp = 0.f;
    #pragma unroll
    for(int r2=0;r2<8;++r2) vsp += vp[lane + 64*r2];
    float Vsum = wsum(vsp);
    float qm = msk[bt];
    float km0 = km_g[lane], km1 = km_g[lane+64];
    size_t pbase = (size_t)(src*512 + bt)*128;
    float p0a = pene[pbase + lane]          + pene[pbase + 131072 + lane];
    float p0b = pene[pbase + 262144 + lane] + pene[pbase + 393216 + lane];
    float p1a = pene[pbase + lane + 64]          + pene[pbase + 131072 + lane + 64];
    float p1b = pene[pbase + 262144 + lane + 64] + pene[pbase + 393216 + lane + 64];
    float s0v = Vsum - 2.f*(p0a + p0b);
    float s1v = Vsum - 2.f*(p1a + p1b);
    float a0 = s0v*km0*qm, a1 = s1v*km1*qm;
    float sm = wsum(a0+a1), sqq = wsum(a0*a0+a1*a1);
    float m0 = km0!=0.f ? s0v : -1e30f;
    float m1 = km1!=0.f ? s1v : -1e30f;
    float mx = wmax(fmaxf(m0,m1));
    float e0 = km0!=0.f ? __expf(s0v-mx) : 0.f;
    float e1 = km1!=0.f ? __expf(s1v-mx) : 0.f;
    float den = wsum(e0+e1);
    float mean = sm/128.f;
    float inv  = rsqrtf(sqq/128.f - mean*mean + LNEPS);
    al[(size_t)bt*128 + lane]      = (a0-mean)*inv;
    al[(size_t)bt*128 + lane + 64] = (a1-mean)*inv;
    float rden = 1.f/den;
    aw_lds[wv][lane]      = e0*rden;
    aw_lds[wv][lane+64]   = e1*rden;
    if(lane==0) qm_lds[wv] = qm;
  }
  __syncthreads();
  {
    float acc[4][2] = {};
    const float* kb = kg + (size_t)b*128*512;
    for(int s=0;s<128;++s){
      float kv0 = kb[(size_t)s*512 + tid];
      float kv1 = kb[(size_t)s*512 + tid + 256];
      #pragma unroll
      for(int w=0;w<4;++w){
        float a = aw_lds[w][s];
        acc[w][0] = __builtin_fmaf(a, kv0, acc[w][0]);
        acc[w][1] = __builtin_fmaf(a, kv1, acc[w][1]);
      }
    }
    #pragma unroll
    for(int w=0;w<4;++w){
      float qm = qm_lds[w];
      size_t o = (size_t)(b*64 + tq*4 + w)*512;
      cc[o + tid]       = qm*acc[w][0];
      cc[o + tid + 256] = qm*acc[w][1];
    }
  }
}

// ---------------- out: gate + stats-reduce + LN*p0 + pad + hash-patched store ----------------
__global__ __launch_bounds__(256) void k_out(const u16* logits, const float2* pstats,
    const float* al1, const float* al2, const float* c1, const float* c2,
    const float* tgt, const float* gw, const float* gb,
    const int* map1, const int* map2, float* out)
{
  int row = blockIdx.x>>2, q = blockIdx.x&3, b = row>>6;
  int tid = threadIdx.x, lane = tid&63, wv = tid>>6;
  __shared__ float gred[4][3], rs[4], rq[4], st[2], pl_s[3];
  __shared__ int hkey[1024];
  __shared__ float hval[1024];
  __shared__ unsigned int bmap[252];

  #pragma unroll
  for(int r=0;r<4;++r){ hkey[tid+256*r] = -1; hval[tid+256*r] = 0.f; }
  if(tid < 252) bmap[tid] = 0u;

  {
    float t0v = tgt[(size_t)row*512+tid], t1v = tgt[(size_t)row*512+tid+256];
    float c10 = c1[(size_t)row*512+tid],  c11 = c1[(size_t)row*512+tid+256];
    float c20 = c2[(size_t)row*512+tid],  c21 = c2[(size_t)row*512+tid+256];
    #pragma unroll
    for(int p=0;p<3;++p){
      const float* gp = gw + p*1536;
      float a = gp[tid]*t0v + gp[tid+256]*t1v
              + gp[512+tid]*c10 + gp[768+tid]*c11
              + gp[1024+tid]*c20 + gp[1280+tid]*c21;
      a = wsum(a);
      if(lane==0) gred[wv][p] = a;
    }
  }
  {
    float s=0.f, qv=0.f;
    if(tid < 250){ float2 pv = pstats[(size_t)row*250 + tid]; s = pv.x; qv = pv.y; }
    s = wsum(s); qv = wsum(qv);
    if(lane==0){ rs[wv]=s; rq[wv]=qv; }
  }
  __syncthreads();
  if(tid==0){
    float S = rs[0]+rs[1]+rs[2]+rs[3];
    float Q = rq[0]+rq[1]+rq[2]+rq[3];
    float mean = S/(float)NV;
    float var  = Q/(float)NV - mean*mean;
    st[0] = mean; st[1] = rsqrtf(var+LNEPS);
    float g0 = gred[0][0]+gred[1][0]+gred[2][0]+gred[3][0] + gb[0];
    float g1 = gred[0][1]+gred[1][1]+gred[2][1]+gred[3][1] + gb[1];
    float g2 = gred[0][2]+gred[1][2]+gred[2][2]+gred[3][2] + gb[2];
    float m = fmaxf(g0, fmaxf(g1, g2));
    float e0=__expf(g0-m), e1=__expf(g1-m), e2=__expf(g2-m);
    float sI = 1.f/(e0+e1+e2);
    pl_s[0]=e0*sI; pl_s[1]=e1*sI; pl_s[2]=e2*sI;
  }
  __syncthreads();

  int elo = q*8064;
  {
    int src = tid>>7, sl = tid&127;
    int e = (src ? map2 : map1)[b*128 + sl];
    if(e >= elo && e < elo+8064){
      float val = pl_s[1+src] * (src ? al2 : al1)[(size_t)row*128 + sl];
      unsigned int h = ((unsigned int)e * 2654435761u) >> 22;
      for(;;){
        int old = atomicCAS(&hkey[h], -1, e);
        if(old == -1 || old == e){ atomicAdd(&hval[h], val); break; }
        h = (h+1) & 1023;
      }
      int rel = e - elo;
      atomicOr(&bmap[rel>>5], 1u << (rel&31));
    }
  }
  __syncthreads();

  float mean = st[0], inv = st[1], p0 = pl_s[0];
  const u16* Lr = logits + (size_t)row*NV;
  float* orow = out + (size_t)row*NEXT;
  for(int i=q*2016+tid; i<(q+1)*2016; i+=256){
    int e0 = i*4;
    float4 r;
    if(e0 < NV){
      const u16* L = &Lr[e0];
      r.x = p0*(bf2f(L[0])-mean)*inv;
      r.y = p0*(bf2f(L[1])-mean)*inv;
      r.z = p0*(bf2f(L[2])-mean)*inv;
      r.w = p0*(bf2f(L[3])-mean)*inv;
    } else { r.x=r.y=r.z=r.w=0.f; }
    int rel = e0 - elo;
    unsigned int w4 = (bmap[rel>>5] >> (rel&31)) & 0xFu;
    if(w4){
      #pragma unroll
      for(int j=0;j<4;++j){
        if(w4 & (1u<<j)){
          int e = e0 + j;
          unsigned int h = ((unsigned int)e * 2654435761u) >> 22;
          while(hkey[h] != e) h = (h+1) & 1023;
          float pv = hval[h];
          if(j==0) r.x += pv; else if(j==1) r.y += pv; else if(j==2) r.z += pv; else r.w += pv;
        }
      }
    }
    *(float4*)&orow[e0] = r;
  }
}

extern "C" void kernel_launch(void* const* d_in, const int* in_sizes, int n_in,
                              void* d_out, int out_size, void* d_ws, size_t ws_size,
                              hipStream_t stream)
{
  const float* tgt  = (const float*)d_in[0];
  const float* s1k  = (const float*)d_in[1];
  const float* s2k  = (const float*)d_in[2];
  const int*   map1 = (const int*)d_in[3];
  const int*   map2 = (const int*)d_in[4];
  const float* ofw  = (const float*)d_in[5];
  const float* ofb  = (const float*)d_in[6];
  const float* a1w  = (const float*)d_in[7];
  const float* a1b  = (const float*)d_in[8];
  const float* v1   = (const float*)d_in[9];
  const float* a2w  = (const float*)d_in[10];
  const float* a2b  = (const float*)d_in[11];
  const float* v2   = (const float*)d_in[12];
  const float* gw   = (const float*)d_in[13];
  const float* gb   = (const float*)d_in[14];

  float* wsf   = (float*)d_ws;
  float* sq1   = wsf;                    // 262144
  float* sq2   = wsf + 262144;
  float* sk1   = wsf + 524288;           // 524288
  float* sk2   = wsf + 1048576;
  float* al1   = wsf + 1572864;          // 65536
  float* al2   = wsf + 1638400;
  float* msk   = wsf + 1705984;          // 2560
  float* c1    = wsf + 1709568;          // 262144
  float* c2    = wsf + 1971712;
  float* pene  = wsf + 2233856;          // 524288
  float2* pstats = (float2*)(wsf + 2758144); // 512*250 float2
  u16*  logits = (u16*)(wsf + 3014144);  // 16384000 u16
  u16*  tgtb   = (u16*)(wsf + 11206144);
  u16*  s1b    = (u16*)(wsf + 11337216);
  u16*  s2b    = (u16*)(wsf + 11599360);
  u16*  a1wb   = (u16*)(wsf + 11861504);
  u16*  a2wb   = (u16*)(wsf + 12123648);
  u16*  ofwb   = (u16*)(wsf + 12385792); // 16384000 u16 -> ends ~82 MB
  float* out   = (float*)d_out;

  k_cast_small<<<1152, 256, 0, stream>>>(tgt, s1k, s2k, a1w, a2w, tgtb, s1b, s2b, a1wb, a2wb, msk);
  k_projcast  <<<8128, 256, 0, stream>>>(tgtb, s1b, s2b, a1wb, a2wb, a1b, a2b,
                                         sq1, sk1, sq2, sk2, ofw, ofwb);
  k_bigen     <<<3024, 256, 0, stream>>>(tgtb, ofwb, ofb, logits, pstats,
                                         sq1, sq2, sk1, sk2, v1, v2, pene);
  k_sm        <<<256, 256, 0, stream>>>(pene, v1, v2, s1k, s2k, msk, al1, al2, c1, c2);
  k_out       <<<2048, 256, 0, stream>>>(logits, pstats, al1, al2, c1, c2, tgt, gw, gb, map1, map2, out);
}